// Round 12
// baseline (730.732 us; speedup 1.0000x reference)
//
#include <hip/hip_runtime.h>
#include <math.h>

typedef unsigned short u16;
typedef unsigned int   u32;
typedef __attribute__((ext_vector_type(8))) _Float16 half8;
typedef __attribute__((ext_vector_type(4))) float    f32x4;

#define PI_F 3.14159265358979323846f

__device__ __forceinline__ float lrelu_f(float x){ return x >= 0.f ? x : 0.05f*x; }
__device__ __forceinline__ u16 f2h(float f){ _Float16 h = (_Float16)f; u16 u; __builtin_memcpy(&u,&h,2); return u; }
__device__ __forceinline__ float h2f(u16 u){ _Float16 h; __builtin_memcpy(&h,&u,2); return (float)h; }

// ---------------------------------------------------------------------------
// Sphere gather tables, COMPACT: tab[n*25 + uv] = lat*Wp + lon (u16, padded
// in-slab absolute address). lat/lon independent of ci -> 25 entries per n.
// Decode via the xu C-order-reshape flat inversion (R9 lesson).
// R11 lesson (NaN post-mortem): for a tile spanning conv rows {oh_lo,oh_lo+1},
// ohg = floor((3*ohc+u)/3) reaches oh_lo+2 (u up to 4), so
// lat in [2*oh_lo-1, 2*oh_lo+5] -> SEVEN slab rows (NROWS=7), not 5.
// ---------------------------------------------------------------------------
struct TabP { u16* tab; int OW, Wo, H, W, Wp, NTOT; };

__global__ void k_stab(TabP p0, TabP p1)
{
    TabP p = blockIdx.y ? p1 : p0;
    int i = blockIdx.x*blockDim.x + threadIdx.x;
    if (i >= p.NTOT*25) return;
    int n = i/25, uv = i%25;
    int ohc = n/p.OW, owc = n%p.OW;
    int r = ohc*3 + uv/5, c = owc*3 + uv%5;
    int flat = r*(p.Wo*3) + c;
    int ohg = flat/(p.Wo*9), rem = flat%(p.Wo*9);
    int owg = rem/9, r3 = rem%9;
    int kh = r3/3, kw = r3%3;
    int ihc = min(ohg*2, p.H-1);
    int lat = min(max(ihc+kh-1, 0), p.H-1);
    float phi = ((float)lat+0.5f)/(float)p.H*PI_F - 0.5f*PI_F;
    float ca  = fmaxf(fabsf(cosf(phi)), 1e-3f);
    float d   = fminf(0.8f/ca, 4.0f);
    float jw  = (float)((owg*2)%p.W);
    float lonf = rintf(jw + d*(float)(kw-1));
    int lon = (int)lonf % p.W; if (lon < 0) lon += p.W;
    p.tab[i] = (u16)(lat*p.Wp + lon);
}

// ---------------------------------------------------------------------------
// Weights, CHUNK-PADDED layout [co][ch][KCm]: col j of chunk ch is
// k = ch*KCd + j for j < KCd, zero otherwise (so MFMA pad columns are inert).
// Sphere: fold avg_pool3(conv3x3) -> effective 5x5/stride3.
// ---------------------------------------------------------------------------
struct WsP { const float* w3; u16* wh; int CO, CI, CIC, NCH, KCd, KCm; };

__global__ void k_wsph(WsP p0, WsP p1)
{
    WsP p = blockIdx.y ? p1 : p0;
    int i = blockIdx.x*blockDim.x + threadIdx.x;
    if (i >= p.CO*p.NCH*p.KCm) return;
    int j = i % p.KCm, t = i / p.KCm;
    int ch = t % p.NCH, co = t / p.NCH;
    float s = 0.f;
    if (j < p.KCd){
        int ci = ch*p.CIC + j/25;
        int uv = j%25, u = uv/5, v = uv%5;
        const float* w = p.w3 + (co*p.CI + ci)*9;
        int pl0 = max(0, u-2), pl1 = min(2, u);
        int q0 = max(0, v-2), q1 = min(2, v);
        for (int pl=pl0; pl<=pl1; ++pl)
            for (int q=q0; q<=q1; ++q) s += w[pl*3+q];
        s *= (1.0f/9.0f);
    }
    p.wh[i] = f2h(s);
}

struct WdP { const float* w; u16* wh; int CO, CI, CIC, NCH, KPQ, KCd, KCm; };

__global__ void k_wdir(WdP p0, WdP p1, WdP p2, WdP p3)
{
    WdP p = (blockIdx.y==0)?p0 : (blockIdx.y==1)?p1 : (blockIdx.y==2)?p2 : p3;
    int i = blockIdx.x*blockDim.x + threadIdx.x;
    if (i >= p.CO*p.NCH*p.KCm) return;
    int j = i % p.KCm, t = i / p.KCm;
    int ch = t % p.NCH, co = t / p.NCH;
    float s = 0.f;
    if (j < p.KCd){
        int ci = ch*p.CIC + j/p.KPQ;
        int r2 = j % p.KPQ;
        s = p.w[(size_t)(co*p.CI + ci)*p.KPQ + r2];
    }
    p.wh[i] = f2h(s);
}

// ---------------------------------------------------------------------------
// Unified MFMA conv engine, ZERO global latency in the inner loop (R10 lesson:
// the fmap->gather dependent chain was the bottleneck, not line counts).
// Per chunk (CIC input channels):
//   phase1: coalesced-copy the needed input ROWS into LDS slab  +  sB weights
//   phase2: build im2col sA by LDS->LDS gather
//           direct: addr = lanebase(n) + ktab[k]   (ktab: tiny in-LDS table)
//           sphere: addr = ci*(NROWS*Wp) + tab[n*25+uv] - r0*Wp  (tab: L2-hot)
//   phase3: MFMA 16x16x32 f16 (fragment mapping unchanged, R7-verified)
// NROWS bounds (R11 NaN post-mortem): sphere = 7; direct = KH + S*(row-span-1)
// where row-span counts oh values a NPAD tile can cross (conv2: 3 -> NROWS=5).
// ---------------------------------------------------------------------------
template<typename IN_T, bool SPH, int CO,int OW,int NTOT,int NB,int BSTRIDE,
         int IH,int IW,int Wp,int NROWS,int S,int KPQ,int KW,
         int CIC,int NCH,int KCd,int KCm,int KCp,int NT_N,int NT_CO>
__global__ __launch_bounds__(256) void k_conv(
    const IN_T* __restrict__ in, const u16* __restrict__ tab,
    const u16* __restrict__ wh,
    const float* __restrict__ bg, const float* __restrict__ bb,
    const float* __restrict__ bm, const float* __restrict__ bv,
    u16* __restrict__ out)
{
    constexpr int NPAD = NT_N*16;
    constexpr int TPW  = (NT_N*NT_CO)/4;
    static_assert((NT_N*NT_CO) % 4 == 0, "tiles split across 4 waves");
    static_assert(KCd % 2 == 0 && KCm % 32 == 0 && KCp % 8 == 0, "tiling");
    __shared__ __align__(16) u16 sraw[CIC*NROWS*Wp];
    __shared__ __align__(16) u16 sA[NPAD*KCp];
    __shared__ __align__(16) u16 sB[CO*KCp];
    __shared__ u32 ktab[KCd];

    int b  = blockIdx.x / NB;
    int n0 = (blockIdx.x % NB)*NPAD;
    int tid = threadIdx.x;
    int oh_lo = n0/OW;
    int r0  = SPH ? max(2*oh_lo-1, 0) : oh_lo*S;
    int NRa = min(NROWS, IH - r0);
    const IN_T* xb = in + (size_t)b*BSTRIDE;

    if constexpr (!SPH){
        if (tid < KCd){
            int ci = tid/KPQ, r2 = tid%KPQ;
            ktab[tid] = (u32)((ci*NROWS + r2/KW)*Wp + r2%KW);
        }
    }
    if constexpr (KCm > KCd){
        constexpr int PADW = KCm - KCd;
        for (int e = tid; e < NPAD*PADW; e += 256)
            sA[(e/PADW)*KCp + KCd + e%PADW] = 0;
    }

    int w = tid >> 6, lane = tid & 63, l15 = lane & 15, l4 = lane >> 4;
    int nt = w % NT_N;
    f32x4 acc[TPW];
    #pragma unroll
    for (int j=0;j<TPW;++j) acc[j] = (f32x4){0.f,0.f,0.f,0.f};

    for (int ch = 0; ch < NCH; ++ch){
        if (ch) __syncthreads();                       // prev MFMA done
        // phase1a: slab rows (coalesced)
        for (int e = tid; e < CIC*NROWS*IW; e += 256){
            int col = e % IW;
            int t   = e / IW;
            int rr  = t % NROWS;
            int ci  = t / NROWS;
            if (rr < NRa){
                u16 v;
                if constexpr (sizeof(IN_T)==4)
                    v = f2h(xb[((size_t)(ch*CIC+ci)*IH + r0+rr)*IW + col]);
                else
                    v = xb[((size_t)(ch*CIC+ci)*IH + r0+rr)*IW + col];
                sraw[(ci*NROWS+rr)*Wp + col] = v;
            }
        }
        // phase1b: weights (16B copies)
        constexpr int W8 = KCm/8;
        for (int i = tid; i < CO*W8; i += 256){
            int co = i / W8, j = (i - co*W8)*8;
            uint4 v = *reinterpret_cast<const uint4*>(wh + ((size_t)co*NCH + ch)*KCm + j);
            *reinterpret_cast<uint4*>(&sB[co*KCp + j]) = v;
        }
        __syncthreads();
        // phase2: sA build (LDS->LDS)
        constexpr int HKD = KCd/2;
        for (int i = tid; i < NPAD*HKD; i += 256){
            int n_l = i / HKD;
            int k0  = (i - n_l*HKD)*2;
            int n_g = min(n0 + n_l, NTOT-1);
            u16 a0, a1;
            if constexpr (SPH){
                int ci = k0/25, uv0 = k0 - ci*25;
                int ci1 = ci, uv1 = uv0 + 1;
                if (uv0 == 24){ ci1 = ci+1; uv1 = 0; }
                int tb = n_g*25, lb = r0*Wp;
                a0 = sraw[ci *(NROWS*Wp) + (int)tab[tb+uv0] - lb];
                a1 = sraw[ci1*(NROWS*Wp) + (int)tab[tb+uv1] - lb];
            } else {
                int oh = n_g/OW, ow = n_g - oh*OW;
                int base = (oh*S - r0)*Wp + ow*S;
                a0 = sraw[base + (int)ktab[k0]];
                a1 = sraw[base + (int)ktab[k0+1]];
            }
            *reinterpret_cast<u32*>(&sA[n_l*KCp + k0]) = (u32)a0 | ((u32)a1 << 16);
        }
        __syncthreads();
        // phase3: MFMA
        #pragma unroll
        for (int ks = 0; ks < KCm/32; ++ks){
            half8 a = *reinterpret_cast<const half8*>(&sA[(nt*16 + l15)*KCp + ks*32 + l4*8]);
            #pragma unroll
            for (int j=0;j<TPW;++j){
                int ct = (w + j*4)/NT_N;
                half8 bf = *reinterpret_cast<const half8*>(&sB[(ct*16 + l15)*KCp + ks*32 + l4*8]);
                acc[j] = __builtin_amdgcn_mfma_f32_16x16x32_f16(a, bf, acc[j], 0, 0, 0);
            }
        }
    }
    // epilogue: BN + lrelu, flat [b][co][NTOT] f16
    #pragma unroll
    for (int j=0;j<TPW;++j){
        int ct = (w + j*4)/NT_N;
        int co = ct*16 + l15;
        float inv = bg[co]*rsqrtf(bv[co]+1e-5f);
        float shv = bb[co] - bm[co]*inv;
        size_t ob = (size_t)(b*CO + co)*NTOT;
        #pragma unroll
        for (int r=0;r<4;++r){
            int gn = n0 + nt*16 + l4*4 + r;
            if (gn < NTOT) out[ob + gn] = f2h(lrelu_f(fmaf(acc[j][r], inv, shv)));
        }
    }
}

// ---------------------------------------------------------------------------
// fused = lrelu(h5_flat @ proj_w.T + v @ vproj_w.T + vproj_b)   (h5 is f16)
// ---------------------------------------------------------------------------
__global__ __launch_bounds__(256) void k_head(
    const u16* __restrict__ h5, const float* __restrict__ vin,
    const float* __restrict__ proj_w, const float* __restrict__ vproj_w,
    const float* __restrict__ vproj_b, float* __restrict__ fused)
{
    __shared__ __align__(16) float sh[2560];
    __shared__ float sv[9];
    int b = blockIdx.x, tid = threadIdx.x;
    for (int i = tid; i < 2560; i += 256) sh[i] = h2f(h5[(size_t)b*2560 + i]);
    if (tid < 9) sv[tid] = vin[b*9 + tid];
    __syncthreads();
    const float* pw = proj_w + (size_t)tid*2560;
    float acc = 0.f;
    for (int k=0;k<2560;k+=4){
        float4 s4 = *reinterpret_cast<const float4*>(sh+k);
        float4 w4 = *reinterpret_cast<const float4*>(pw+k);
        acc = fmaf(s4.x,w4.x, fmaf(s4.y,w4.y, fmaf(s4.z,w4.z, fmaf(s4.w,w4.w, acc))));
    }
    float av = 0.f;
    #pragma unroll
    for (int k=0;k<9;++k) av += sv[k]*vproj_w[tid*9+k];
    fused[b*256+tid] = lrelu_f(acc + av + vproj_b[tid]);
}

// ---------------------------------------------------------------------------
// GRU cell
// ---------------------------------------------------------------------------
__global__ __launch_bounds__(256) void k_gru(
    const float* __restrict__ fused, const float* __restrict__ hx,
    const float* __restrict__ wih, const float* __restrict__ whh,
    const float* __restrict__ bih, const float* __restrict__ bhh,
    float* __restrict__ hx_new)
{
    __shared__ __align__(16) float sf[256];
    __shared__ __align__(16) float shx[256];
    int b = blockIdx.x, j = threadIdx.x;
    sf[j]  = fused[b*256+j];
    shx[j] = hx[b*256+j];
    __syncthreads();
    float ga[3], gb[3];
    #pragma unroll
    for (int gi=0; gi<3; ++gi){
        const float* wi = wih + ((size_t)gi*256 + j)*256;
        const float* wh = whh + ((size_t)gi*256 + j)*256;
        float a = 0.f, c = 0.f;
        for (int k=0;k<256;k+=4){
            float4 f4  = *reinterpret_cast<const float4*>(sf+k);
            float4 h4  = *reinterpret_cast<const float4*>(shx+k);
            float4 wi4 = *reinterpret_cast<const float4*>(wi+k);
            float4 wh4 = *reinterpret_cast<const float4*>(wh+k);
            a = fmaf(f4.x,wi4.x, fmaf(f4.y,wi4.y, fmaf(f4.z,wi4.z, fmaf(f4.w,wi4.w, a))));
            c = fmaf(h4.x,wh4.x, fmaf(h4.y,wh4.y, fmaf(h4.z,wh4.z, fmaf(h4.w,wh4.w, c))));
        }
        ga[gi] = a + bih[gi*256+j];
        gb[gi] = c + bhh[gi*256+j];
    }
    float r = 1.f/(1.f+expf(-(ga[0]+gb[0])));
    float z = 1.f/(1.f+expf(-(ga[1]+gb[1])));
    float n = tanhf(ga[2] + r*gb[2]);
    hx_new[b*256+j] = (1.f-z)*n + z*shx[j];
}

// act = lrelu(hx_new) @ fc_w.T
__global__ void k_act(const float* __restrict__ hx_new, const float* __restrict__ fc_w,
                      float* __restrict__ act)
{
    int t = blockIdx.x*blockDim.x + threadIdx.x;
    if (t >= 1024) return;
    int b = t >> 2, o = t & 3;
    const float* h = hx_new + b*256;
    const float* w = fc_w + o*256;
    float acc = 0.f;
    for (int k=0;k<256;++k) acc = fmaf(lrelu_f(h[k]), w[k], acc);
    act[t] = acc;
}

extern "C" void kernel_launch(void* const* d_in, const int* in_sizes, int n_in,
                              void* d_out, int out_size, void* d_ws, size_t ws_size,
                              hipStream_t stream)
{
    const float* x      = (const float*)d_in[0];
    const float* vin    = (const float*)d_in[1];
    const float* hx     = (const float*)d_in[2];
    const float* sc0_w  = (const float*)d_in[3];
    const float* bn0g   = (const float*)d_in[4];
    const float* bn0b   = (const float*)d_in[5];
    const float* bn0m   = (const float*)d_in[6];
    const float* bn0v   = (const float*)d_in[7];
    const float* sc1_w  = (const float*)d_in[8];
    const float* bn1g   = (const float*)d_in[9];
    const float* bn1b   = (const float*)d_in[10];
    const float* bn1m   = (const float*)d_in[11];
    const float* bn1v   = (const float*)d_in[12];
    const float* c2_w   = (const float*)d_in[13];
    const float* bn2g   = (const float*)d_in[14];
    const float* bn2b   = (const float*)d_in[15];
    const float* bn2m   = (const float*)d_in[16];
    const float* bn2v   = (const float*)d_in[17];
    const float* c3_w   = (const float*)d_in[18];
    const float* bn3g   = (const float*)d_in[19];
    const float* bn3b   = (const float*)d_in[20];
    const float* bn3m   = (const float*)d_in[21];
    const float* bn3v   = (const float*)d_in[22];
    const float* c4_w   = (const float*)d_in[23];
    const float* bn4g   = (const float*)d_in[24];
    const float* bn4b   = (const float*)d_in[25];
    const float* bn4m   = (const float*)d_in[26];
    const float* bn4v   = (const float*)d_in[27];
    const float* c5_w   = (const float*)d_in[28];
    const float* bn5g   = (const float*)d_in[29];
    const float* bn5b   = (const float*)d_in[30];
    const float* bn5m   = (const float*)d_in[31];
    const float* bn5v   = (const float*)d_in[32];
    const float* proj_w = (const float*)d_in[33];
    const float* vproj_w= (const float*)d_in[34];
    const float* vproj_b= (const float*)d_in[35];
    const float* gru_wih= (const float*)d_in[36];
    const float* gru_whh= (const float*)d_in[37];
    const float* gru_bih= (const float*)d_in[38];
    const float* gru_bhh= (const float*)d_in[39];
    const float* fc_w   = (const float*)d_in[40];

    char* base = (char*)d_ws;
    size_t off = 0;
    auto alloc = [&](size_t bytes)->char*{
        char* p = base + off; off += (bytes + 255) & ~(size_t)255; return p;
    };
    u16* tab0 = (u16*)alloc((size_t)1953*25*2);
    u16* tab1 = (u16*)alloc((size_t)465*25*2);
    u16* wb0  = (u16*)alloc((size_t)32*160*2);        // [co][1][160]
    u16* wb1  = (u16*)alloc((size_t)64*4*224*2);      // [co][4][224]
    u16* wb2  = (u16*)alloc((size_t)64*4*160*2);
    u16* wb3  = (u16*)alloc((size_t)64*2*128*2);
    u16* wb4  = (u16*)alloc((size_t)128*4*160*2);
    u16* wb5  = (u16*)alloc((size_t)128*8*160*2);
    u16* h0   = (u16*)alloc((size_t)256*32*1953*2);
    u16* h1   = (u16*)alloc((size_t)256*64*465*2);
    u16* h2   = (u16*)alloc((size_t)256*64*377*2);
    u16* h3   = (u16*)alloc((size_t)256*64*84*2);
    u16* h4   = (u16*)alloc((size_t)256*128*48*2);
    u16* h5   = (u16*)alloc((size_t)256*128*20*2);
    float* fused = (float*)alloc((size_t)65536*4);

    // ---- one-time precompute (3 launches) ----
    TabP t0 = { tab0, 63, 64, 64, 128, 198, 1953 };
    TabP t1 = { tab1, 31, 32, 31,  63,  66,  465 };
    k_stab<<<dim3((1953*25+255)/256, 2), 256, 0, stream>>>(t0, t1);
    WsP s0 = { sc0_w, wb0, 32,  6,  6, 1, 150, 160 };
    WsP s1 = { sc1_w, wb1, 64, 32,  8, 4, 200, 224 };
    k_wsph<<<dim3((64*4*224+255)/256, 2), 256, 0, stream>>>(s0, s1);
    WdP d2 = { c2_w, wb2,  64,  64, 16, 4, 9, 144, 160 };
    WdP d3 = { c3_w, wb3,  64,  64, 32, 2, 4, 128, 128 };
    WdP d4 = { c4_w, wb4, 128,  64, 16, 4, 9, 144, 160 };
    WdP d5 = { c5_w, wb5, 128, 128, 16, 8, 9, 144, 160 };
    k_wdir<<<dim3((128*8*160+255)/256, 4), 256, 0, stream>>>(d2, d3, d4, d5);

    // ---- backbone ----
    // k_conv<IN_T,SPH,CO,OW,NTOT,NB,BSTRIDE,IH,IW,Wp,NROWS,S,KPQ,KW,
    //        CIC,NCH,KCd,KCm,KCp,NT_N,NT_CO>
    k_conv<float,true,32,63,1953,31,49152, 64,128,198,7,3,25,5, 6,1,150,160,168,4,2>
        <<<256*31, 256, 0, stream>>>(x,  tab0, wb0, bn0g,bn0b,bn0m,bn0v, h0);
    k_conv<u16,true,64,31,465,15,62496, 31,63,66,7,3,25,5, 8,4,200,224,232,2,4>
        <<<256*15, 256, 0, stream>>>(h0, tab1, wb1, bn1g,bn1b,bn1m,bn1v, h1);
    k_conv<u16,false,64,29,377,12,29760, 15,31,34,5,1,9,3, 16,4,144,160,168,2,4>
        <<<256*12, 256, 0, stream>>>(h1, tab1, wb2, bn2g,bn2b,bn2m,bn2v, h2);
    k_conv<u16,false,64,14,84,3,24128, 13,29,30,6,2,4,2, 32,2,128,128,136,2,4>
        <<<256*3,  256, 0, stream>>>(h2, tab1, wb3, bn3g,bn3b,bn3m,bn3v, h3);
    k_conv<u16,false,128,12,48,3,5376, 6,14,14,4,1,9,3, 16,4,144,160,168,1,8>
        <<<256*3,  256, 0, stream>>>(h3, tab1, wb4, bn4g,bn4b,bn4m,bn4v, h4);
    k_conv<u16,false,128,10,20,2,6144, 4,12,14,4,1,9,3, 16,8,144,160,168,1,8>
        <<<256*2,  256, 0, stream>>>(h4, tab1, wb5, bn5g,bn5b,bn5m,bn5v, h5);

    // ---- head ----
    k_head<<<256, 256, 0, stream>>>(h5, vin, proj_w, vproj_w, vproj_b, fused);
    float* outp = (float*)d_out;
    k_gru<<<256, 256, 0, stream>>>(fused, hx, gru_wih, gru_whh, gru_bih, gru_bhh, outp + 1024);
    k_act<<<4, 256, 0, stream>>>(outp + 1024, fc_w, outp);
}

// Round 13
// 665.310 us; speedup vs baseline: 1.0983x; 1.0983x over previous
//
#include <hip/hip_runtime.h>
#include <math.h>

typedef unsigned short u16;
typedef unsigned int   u32;
typedef __attribute__((ext_vector_type(8))) _Float16 half8;
typedef __attribute__((ext_vector_type(4))) float    f32x4;

#define PI_F 3.14159265358979323846f

__device__ __forceinline__ float lrelu_f(float x){ return x >= 0.f ? x : 0.05f*x; }
__device__ __forceinline__ u16 f2h(float f){ _Float16 h = (_Float16)f; u16 u; __builtin_memcpy(&u,&h,2); return u; }
__device__ __forceinline__ float h2f(u16 u){ _Float16 h; __builtin_memcpy(&h,&u,2); return (float)h; }

// ---------------------------------------------------------------------------
// Index map in xu RASTER order (flat = oh*(Wo*9)+ow*9+kh*3+kw = r*(Wo*3)+c,
// the C-order reshape — R0-proven body, R9 lesson: never decode blockwise).
// map[flat] = lat*W + lon  (within-plane gather offset).
// ---------------------------------------------------------------------------
struct MapP { int* map; int H, W, Wo, total; };

__global__ void k_map2(MapP p0, MapP p1)
{
    MapP p = blockIdx.y ? p1 : p0;
    int i = blockIdx.x*blockDim.x + threadIdx.x;
    if (i >= p.total) return;
    int oh  = i / (p.Wo*9);
    int rem = i % (p.Wo*9);
    int ow  = rem / 9;
    int r2  = rem % 9;
    int kh  = r2/3, kw = r2%3;
    int ihc = min(oh*2, p.H-1);
    int lat = min(max(ihc + kh - 1, 0), p.H-1);
    float phi = ((float)lat + 0.5f)/(float)p.H * PI_F - 0.5f*PI_F;
    float ca  = fmaxf(fabsf(cosf(phi)), 1e-3f);
    float d   = fminf(0.8f/ca, 4.0f);
    float jw  = (float)((ow*2) % p.W);
    float lonf = rintf(jw + d*(float)(kw-1));   // np.round == rint (half-even)
    int lon = (int)lonf % p.W; if (lon < 0) lon += p.W;
    p.map[i] = lat*p.W + lon;
}

// ---------------------------------------------------------------------------
// xu materialization: one-shot streaming gather (R12 lesson: do the irregular
// gather ONCE, coalesced, instead of inside every conv block's staging loop).
// out[p][c] = cvt(in[p][map[c]]);  p = b*CI+ci plane (blockIdx.y), c = xu pos.
// ---------------------------------------------------------------------------
template<typename IN_T>
__global__ void k_xu(const IN_T* __restrict__ in, const int* __restrict__ map,
                     u16* __restrict__ out, int NIMG, int IPLANE)
{
    int c = blockIdx.x*blockDim.x + threadIdx.x;
    if (c >= NIMG) return;
    int p = blockIdx.y;
    int m = map[c];
    u16 v;
    if constexpr (sizeof(IN_T)==4) v = f2h(in[(size_t)p*IPLANE + m]);
    else                           v = in[(size_t)p*IPLANE + m];
    out[(size_t)p*NIMG + c] = v;
}

// ---------------------------------------------------------------------------
// Weights, CHUNK-PADDED [co][ch][KCm]: col j of chunk ch is k=ch*KCd+j for
// j<KCd, zero otherwise (pad columns inert in MFMA).
// Sphere: fold avg_pool3(conv3x3) -> effective 5x5/stride3 (R4-verified).
// ---------------------------------------------------------------------------
struct WsP { const float* w3; u16* wh; int CO, CI, CIC, NCH, KCd, KCm; };

__global__ void k_wsph(WsP p0, WsP p1)
{
    WsP p = blockIdx.y ? p1 : p0;
    int i = blockIdx.x*blockDim.x + threadIdx.x;
    if (i >= p.CO*p.NCH*p.KCm) return;
    int j = i % p.KCm, t = i / p.KCm;
    int ch = t % p.NCH, co = t / p.NCH;
    float s = 0.f;
    if (j < p.KCd){
        int ci = ch*p.CIC + j/25;
        int uv = j%25, u = uv/5, v = uv%5;
        const float* w = p.w3 + (co*p.CI + ci)*9;
        int pl0 = max(0, u-2), pl1 = min(2, u);
        int q0 = max(0, v-2), q1 = min(2, v);
        for (int pl=pl0; pl<=pl1; ++pl)
            for (int q=q0; q<=q1; ++q) s += w[pl*3+q];
        s *= (1.0f/9.0f);
    }
    p.wh[i] = f2h(s);
}

struct WdP { const float* w; u16* wh; int CO, CI, CIC, NCH, KPQ, KCd, KCm; };

__global__ void k_wdir(WdP p0, WdP p1, WdP p2, WdP p3)
{
    WdP p = (blockIdx.y==0)?p0 : (blockIdx.y==1)?p1 : (blockIdx.y==2)?p2 : p3;
    int i = blockIdx.x*blockDim.x + threadIdx.x;
    if (i >= p.CO*p.NCH*p.KCm) return;
    int j = i % p.KCm, t = i / p.KCm;
    int ch = t % p.NCH, co = t / p.NCH;
    float s = 0.f;
    if (j < p.KCd){
        int ci = ch*p.CIC + j/p.KPQ;
        int r2 = j % p.KPQ;
        s = p.w[(size_t)(co*p.CI + ci)*p.KPQ + r2];
    }
    p.wh[i] = f2h(s);
}

// ---------------------------------------------------------------------------
// Direct MFMA conv engine on a dense u16 image (all 6 layers; sphere layers
// run on materialized xu). Staging is n-fast: lanes = consecutive output
// positions at (wave-uniform) k -> row-local global reads (~4 lines/wave),
// index math is ~8 VALU/lane, NO table lookups (R10/R12 lesson: kill the
// dependent index->gather chain). One barrier pair per K-chunk.
// Fragment layout (guide §3, m89-verified): A/B lane&15 = M/N, k=(lane>>4)*8+j;
// D col=lane&15, row=(lane>>4)*4+reg.
// ---------------------------------------------------------------------------
template<int CO,int OW,int NTOT,int NB,int BSTRIDE,int IH,int IW,
         int KH,int KW,int S,int KPQ,int CIC,
         int NCH,int KCd,int KCm,int KCp,int NT_N,int NT_CO>
__global__ __launch_bounds__(256) void k_dconv(
    const u16* __restrict__ in, const u16* __restrict__ wh,
    const float* __restrict__ bg, const float* __restrict__ bb,
    const float* __restrict__ bm, const float* __restrict__ bv,
    u16* __restrict__ out)
{
    constexpr int NPAD = NT_N*16;
    constexpr int TPW  = (NT_N*NT_CO)/4;
    static_assert((NT_N*NT_CO) % 4 == 0, "tiles split across 4 waves");
    static_assert(KCd == CIC*KPQ, "chunk = whole channels");
    static_assert(KCd % 2 == 0 && KCm % 32 == 0 && KCp % 8 == 0, "tiling");
    static_assert((NPAD & (NPAD-1)) == 0, "NPAD pow2");
    __shared__ __align__(16) u16 sA[NPAD*KCp];
    __shared__ __align__(16) u16 sB[CO*KCp];

    int b  = blockIdx.x / NB;
    int n0 = (blockIdx.x % NB)*NPAD;
    int tid = threadIdx.x;
    const u16* xb = in + (size_t)b*BSTRIDE;

    if constexpr (KCm > KCd){
        constexpr int PADW = KCm - KCd;
        for (int e = tid; e < NPAD*PADW; e += 256)
            sA[(e/PADW)*KCp + KCd + e%PADW] = 0;
    }

    int w = tid >> 6, lane = tid & 63, l15 = lane & 15, l4 = lane >> 4;
    int nt = w % NT_N;
    f32x4 acc[TPW];
    #pragma unroll
    for (int j=0;j<TPW;++j) acc[j] = (f32x4){0.f,0.f,0.f,0.f};

    for (int ch = 0; ch < NCH; ++ch){
        if (ch) __syncthreads();
        const u16* xc = xb + (size_t)ch*CIC*IH*IW;
        // stage A: n-fast im2col (2 adjacent k per thread -> u32 write)
        constexpr int HKD = KCd/2;
        for (int i = tid; i < NPAD*HKD; i += 256){
            int n_l = i & (NPAD-1);
            int k0  = (i/NPAD)*2;
            int n_g = min(n0 + n_l, NTOT-1);
            int oh = n_g/OW, ow = n_g - oh*OW;
            int base = (oh*S)*IW + ow*S;
            int c0 = k0/KPQ, r0 = k0 - c0*KPQ, u0 = r0/KW, v0 = r0 - u0*KW;
            int k1 = k0+1;
            int c1 = k1/KPQ, r1 = k1 - c1*KPQ, u1 = r1/KW, v1 = r1 - u1*KW;
            u16 a0 = xc[(c0*IH + u0)*IW + base + v0];
            u16 a1 = xc[(c1*IH + u1)*IW + base + v1];
            *reinterpret_cast<u32*>(&sA[n_l*KCp + k0]) = (u32)a0 | ((u32)a1 << 16);
        }
        // stage B: weights (16B copies)
        constexpr int W8 = KCm/8;
        for (int i = tid; i < CO*W8; i += 256){
            int co = i / W8, j = (i - co*W8)*8;
            uint4 v = *reinterpret_cast<const uint4*>(wh + ((size_t)co*NCH + ch)*KCm + j);
            *reinterpret_cast<uint4*>(&sB[co*KCp + j]) = v;
        }
        __syncthreads();
        // MFMA
        #pragma unroll
        for (int ks = 0; ks < KCm/32; ++ks){
            half8 a = *reinterpret_cast<const half8*>(&sA[(nt*16 + l15)*KCp + ks*32 + l4*8]);
            #pragma unroll
            for (int j=0;j<TPW;++j){
                int ct = (w + j*4)/NT_N;
                half8 bf = *reinterpret_cast<const half8*>(&sB[(ct*16 + l15)*KCp + ks*32 + l4*8]);
                acc[j] = __builtin_amdgcn_mfma_f32_16x16x32_f16(a, bf, acc[j], 0, 0, 0);
            }
        }
    }
    // epilogue: BN + lrelu, flat [b][co][NTOT] f16
    #pragma unroll
    for (int j=0;j<TPW;++j){
        int ct = (w + j*4)/NT_N;
        int co = ct*16 + l15;
        float inv = bg[co]*rsqrtf(bv[co]+1e-5f);
        float shv = bb[co] - bm[co]*inv;
        size_t ob = (size_t)(b*CO + co)*NTOT;
        #pragma unroll
        for (int r=0;r<4;++r){
            int gn = n0 + nt*16 + l4*4 + r;
            if (gn < NTOT) out[ob + gn] = f2h(lrelu_f(fmaf(acc[j][r], inv, shv)));
        }
    }
}

// ---------------------------------------------------------------------------
// fused = lrelu(h5_flat @ proj_w.T + v @ vproj_w.T + vproj_b)   (h5 is f16)
// ---------------------------------------------------------------------------
__global__ __launch_bounds__(256) void k_head(
    const u16* __restrict__ h5, const float* __restrict__ vin,
    const float* __restrict__ proj_w, const float* __restrict__ vproj_w,
    const float* __restrict__ vproj_b, float* __restrict__ fused)
{
    __shared__ __align__(16) float sh[2560];
    __shared__ float sv[9];
    int b = blockIdx.x, tid = threadIdx.x;
    for (int i = tid; i < 2560; i += 256) sh[i] = h2f(h5[(size_t)b*2560 + i]);
    if (tid < 9) sv[tid] = vin[b*9 + tid];
    __syncthreads();
    const float* pw = proj_w + (size_t)tid*2560;
    float acc = 0.f;
    for (int k=0;k<2560;k+=4){
        float4 s4 = *reinterpret_cast<const float4*>(sh+k);
        float4 w4 = *reinterpret_cast<const float4*>(pw+k);
        acc = fmaf(s4.x,w4.x, fmaf(s4.y,w4.y, fmaf(s4.z,w4.z, fmaf(s4.w,w4.w, acc))));
    }
    float av = 0.f;
    #pragma unroll
    for (int k=0;k<9;++k) av += sv[k]*vproj_w[tid*9+k];
    fused[b*256+tid] = lrelu_f(acc + av + vproj_b[tid]);
}

// ---------------------------------------------------------------------------
// GRU cell
// ---------------------------------------------------------------------------
__global__ __launch_bounds__(256) void k_gru(
    const float* __restrict__ fused, const float* __restrict__ hx,
    const float* __restrict__ wih, const float* __restrict__ whh,
    const float* __restrict__ bih, const float* __restrict__ bhh,
    float* __restrict__ hx_new)
{
    __shared__ __align__(16) float sf[256];
    __shared__ __align__(16) float shx[256];
    int b = blockIdx.x, j = threadIdx.x;
    sf[j]  = fused[b*256+j];
    shx[j] = hx[b*256+j];
    __syncthreads();
    float ga[3], gb[3];
    #pragma unroll
    for (int gi=0; gi<3; ++gi){
        const float* wi = wih + ((size_t)gi*256 + j)*256;
        const float* wh = whh + ((size_t)gi*256 + j)*256;
        float a = 0.f, c = 0.f;
        for (int k=0;k<256;k+=4){
            float4 f4  = *reinterpret_cast<const float4*>(sf+k);
            float4 h4  = *reinterpret_cast<const float4*>(shx+k);
            float4 wi4 = *reinterpret_cast<const float4*>(wi+k);
            float4 wh4 = *reinterpret_cast<const float4*>(wh+k);
            a = fmaf(f4.x,wi4.x, fmaf(f4.y,wi4.y, fmaf(f4.z,wi4.z, fmaf(f4.w,wi4.w, a))));
            c = fmaf(h4.x,wh4.x, fmaf(h4.y,wh4.y, fmaf(h4.z,wh4.z, fmaf(h4.w,wh4.w, c))));
        }
        ga[gi] = a + bih[gi*256+j];
        gb[gi] = c + bhh[gi*256+j];
    }
    float r = 1.f/(1.f+expf(-(ga[0]+gb[0])));
    float z = 1.f/(1.f+expf(-(ga[1]+gb[1])));
    float n = tanhf(ga[2] + r*gb[2]);
    hx_new[b*256+j] = (1.f-z)*n + z*shx[j];
}

// act = lrelu(hx_new) @ fc_w.T
__global__ void k_act(const float* __restrict__ hx_new, const float* __restrict__ fc_w,
                      float* __restrict__ act)
{
    int t = blockIdx.x*blockDim.x + threadIdx.x;
    if (t >= 1024) return;
    int b = t >> 2, o = t & 3;
    const float* h = hx_new + b*256;
    const float* w = fc_w + o*256;
    float acc = 0.f;
    for (int k=0;k<256;++k) acc = fmaf(lrelu_f(h[k]), w[k], acc);
    act[t] = acc;
}

extern "C" void kernel_launch(void* const* d_in, const int* in_sizes, int n_in,
                              void* d_out, int out_size, void* d_ws, size_t ws_size,
                              hipStream_t stream)
{
    const float* x      = (const float*)d_in[0];
    const float* vin    = (const float*)d_in[1];
    const float* hx     = (const float*)d_in[2];
    const float* sc0_w  = (const float*)d_in[3];
    const float* bn0g   = (const float*)d_in[4];
    const float* bn0b   = (const float*)d_in[5];
    const float* bn0m   = (const float*)d_in[6];
    const float* bn0v   = (const float*)d_in[7];
    const float* sc1_w  = (const float*)d_in[8];
    const float* bn1g   = (const float*)d_in[9];
    const float* bn1b   = (const float*)d_in[10];
    const float* bn1m   = (const float*)d_in[11];
    const float* bn1v   = (const float*)d_in[12];
    const float* c2_w   = (const float*)d_in[13];
    const float* bn2g   = (const float*)d_in[14];
    const float* bn2b   = (const float*)d_in[15];
    const float* bn2m   = (const float*)d_in[16];
    const float* bn2v   = (const float*)d_in[17];
    const float* c3_w   = (const float*)d_in[18];
    const float* bn3g   = (const float*)d_in[19];
    const float* bn3b   = (const float*)d_in[20];
    const float* bn3m   = (const float*)d_in[21];
    const float* bn3v   = (const float*)d_in[22];
    const float* c4_w   = (const float*)d_in[23];
    const float* bn4g   = (const float*)d_in[24];
    const float* bn4b   = (const float*)d_in[25];
    const float* bn4m   = (const float*)d_in[26];
    const float* bn4v   = (const float*)d_in[27];
    const float* c5_w   = (const float*)d_in[28];
    const float* bn5g   = (const float*)d_in[29];
    const float* bn5b   = (const float*)d_in[30];
    const float* bn5m   = (const float*)d_in[31];
    const float* bn5v   = (const float*)d_in[32];
    const float* proj_w = (const float*)d_in[33];
    const float* vproj_w= (const float*)d_in[34];
    const float* vproj_b= (const float*)d_in[35];
    const float* gru_wih= (const float*)d_in[36];
    const float* gru_whh= (const float*)d_in[37];
    const float* gru_bih= (const float*)d_in[38];
    const float* gru_bhh= (const float*)d_in[39];
    const float* fc_w   = (const float*)d_in[40];

    char* base = (char*)d_ws;
    size_t off = 0;
    auto alloc = [&](size_t bytes)->char*{
        char* p = base + off; off += (bytes + 255) & ~(size_t)255; return p;
    };
    int* map0 = (int*)alloc((size_t)96*192*4);          // xu0 raster map
    int* map1 = (int*)alloc((size_t)48*96*4);           // xu1 raster map
    u16* wb0  = (u16*)alloc((size_t)32*1*160*2);
    u16* wb1  = (u16*)alloc((size_t)64*4*224*2);
    u16* wb2  = (u16*)alloc((size_t)64*4*160*2);
    u16* wb3  = (u16*)alloc((size_t)64*2*128*2);
    u16* wb4  = (u16*)alloc((size_t)128*4*160*2);
    u16* wb5  = (u16*)alloc((size_t)128*8*160*2);
    // xu0 (56.6MB) is dead before xu1 (75.5MB) is built -> share one region
    u16* xu   = (u16*)alloc((size_t)256*32*48*96*2);    // max(xu0, xu1)
    u16* h0   = (u16*)alloc((size_t)256*32*1953*2);
    u16* h1   = (u16*)alloc((size_t)256*64*465*2);
    u16* h2   = (u16*)alloc((size_t)256*64*377*2);
    u16* h3   = (u16*)alloc((size_t)256*64*84*2);
    u16* h4   = (u16*)alloc((size_t)256*128*48*2);
    u16* h5   = (u16*)alloc((size_t)256*128*20*2);
    float* fused = (float*)alloc((size_t)65536*4);

    // ---- one-time precompute ----
    MapP m0 = { map0, 64, 128, 64, 96*192 };
    MapP m1 = { map1, 31,  63, 32, 48*96 };
    k_map2<<<dim3((96*192+255)/256, 2), 256, 0, stream>>>(m0, m1);
    WsP s0 = { sc0_w, wb0, 32,  6,  6, 1, 150, 160 };
    WsP s1 = { sc1_w, wb1, 64, 32,  8, 4, 200, 224 };
    k_wsph<<<dim3((64*4*224+255)/256, 2), 256, 0, stream>>>(s0, s1);
    WdP d2 = { c2_w, wb2,  64,  64, 16, 4, 9, 144, 160 };
    WdP d3 = { c3_w, wb3,  64,  64, 32, 2, 4, 128, 128 };
    WdP d4 = { c4_w, wb4, 128,  64, 16, 4, 9, 144, 160 };
    WdP d5 = { c5_w, wb5, 128, 128, 16, 8, 9, 144, 160 };
    k_wdir<<<dim3((128*8*160+255)/256, 4), 256, 0, stream>>>(d2, d3, d4, d5);

    // ---- backbone: materialize xu -> direct MFMA conv ----
    // k_dconv<CO,OW,NTOT,NB,BSTRIDE,IH,IW,KH,KW,S,KPQ,CIC,NCH,KCd,KCm,KCp,NT_N,NT_CO>
    k_xu<float><<<dim3(72, 256*6), 256, 0, stream>>>(x, map0, xu, 96*192, 64*128);
    k_dconv<32,63,1953,31,110592,96,192, 5,5,3,25,6, 1,150,160,168,4,2>
        <<<256*31, 256, 0, stream>>>(xu, wb0, bn0g,bn0b,bn0m,bn0v, h0);
    k_xu<u16><<<dim3(18, 256*32), 256, 0, stream>>>(h0, map1, xu, 48*96, 1953);
    k_dconv<64,31,465,15,147456,48,96, 5,5,3,25,8, 4,200,224,232,2,4>
        <<<256*15, 256, 0, stream>>>(xu, wb1, bn1g,bn1b,bn1m,bn1v, h1);
    k_dconv<64,29,377,12,29760,15,31, 3,3,1,9,16, 4,144,160,168,2,4>
        <<<256*12, 256, 0, stream>>>(h1, wb2, bn2g,bn2b,bn2m,bn2v, h2);
    k_dconv<64,14,84,3,24128,13,29, 2,2,2,4,32, 2,128,128,136,2,4>
        <<<256*3,  256, 0, stream>>>(h2, wb3, bn3g,bn3b,bn3m,bn3v, h3);
    k_dconv<128,12,48,3,5376,6,14, 3,3,1,9,16, 4,144,160,168,1,8>
        <<<256*3,  256, 0, stream>>>(h3, wb4, bn4g,bn4b,bn4m,bn4v, h4);
    k_dconv<128,10,20,2,6144,4,12, 3,3,1,9,16, 8,144,160,168,1,8>
        <<<256*2,  256, 0, stream>>>(h4, wb5, bn5g,bn5b,bn5m,bn5v, h5);

    // ---- head ----
    k_head<<<256, 256, 0, stream>>>(h5, vin, proj_w, vproj_w, vproj_b, fused);
    float* outp = (float*)d_out;
    k_gru<<<256, 256, 0, stream>>>(fused, hx, gru_wih, gru_whh, gru_bih, gru_bhh, outp + 1024);
    k_act<<<4, 256, 0, stream>>>(outp + 1024, fc_w, outp);
}

// Round 14
// 664.822 us; speedup vs baseline: 1.0991x; 1.0007x over previous
//
#include <hip/hip_runtime.h>
#include <math.h>

typedef unsigned short u16;
typedef unsigned int   u32;
typedef __attribute__((ext_vector_type(8))) _Float16 half8;
typedef __attribute__((ext_vector_type(4))) float    f32x4;

#define PI_F 3.14159265358979323846f

__device__ __forceinline__ float lrelu_f(float x){ return x >= 0.f ? x : 0.05f*x; }
__device__ __forceinline__ u16 f2h(float f){ _Float16 h = (_Float16)f; u16 u; __builtin_memcpy(&u,&h,2); return u; }
__device__ __forceinline__ float h2f(u16 u){ _Float16 h; __builtin_memcpy(&h,&u,2); return (float)h; }

// ---------------------------------------------------------------------------
// Index map in xu RASTER order (flat = oh*(Wo*9)+ow*9+kh*3+kw = r*(Wo*3)+c,
// the C-order reshape — R0-proven body, R9 lesson: never decode blockwise).
// map[flat] = lat*W + lon  (within-plane gather offset).
// ---------------------------------------------------------------------------
struct MapP { int* map; int H, W, Wo, total; };

__global__ void k_map2(MapP p0, MapP p1)
{
    MapP p = blockIdx.y ? p1 : p0;
    int i = blockIdx.x*blockDim.x + threadIdx.x;
    if (i >= p.total) return;
    int oh  = i / (p.Wo*9);
    int rem = i % (p.Wo*9);
    int ow  = rem / 9;
    int r2  = rem % 9;
    int kh  = r2/3, kw = r2%3;
    int ihc = min(oh*2, p.H-1);
    int lat = min(max(ihc + kh - 1, 0), p.H-1);
    float phi = ((float)lat + 0.5f)/(float)p.H * PI_F - 0.5f*PI_F;
    float ca  = fmaxf(fabsf(cosf(phi)), 1e-3f);
    float d   = fminf(0.8f/ca, 4.0f);
    float jw  = (float)((ow*2) % p.W);
    float lonf = rintf(jw + d*(float)(kw-1));   // np.round == rint (half-even)
    int lon = (int)lonf % p.W; if (lon < 0) lon += p.W;
    p.map[i] = lat*p.W + lon;
}

// ---------------------------------------------------------------------------
// xu materialization: one-shot streaming gather (R12 lesson: do the irregular
// gather ONCE, coalesced, instead of inside every conv block's staging loop).
// out[p][c] = cvt(in[p][map[c]]);  p = b*CI+ci plane (blockIdx.y), c = xu pos.
// ---------------------------------------------------------------------------
template<typename IN_T>
__global__ void k_xu(const IN_T* __restrict__ in, const int* __restrict__ map,
                     u16* __restrict__ out, int NIMG, int IPLANE)
{
    int c = blockIdx.x*blockDim.x + threadIdx.x;
    if (c >= NIMG) return;
    int p = blockIdx.y;
    int m = map[c];
    u16 v;
    if constexpr (sizeof(IN_T)==4) v = f2h(in[(size_t)p*IPLANE + m]);
    else                           v = in[(size_t)p*IPLANE + m];
    out[(size_t)p*NIMG + c] = v;
}

// ---------------------------------------------------------------------------
// Weights, CHUNK-PADDED [co][ch][KCm]: col j of chunk ch is k=ch*KCd+j for
// j<KCd, zero otherwise (pad columns inert in MFMA).
// Sphere: fold avg_pool3(conv3x3) -> effective 5x5/stride3 (R4-verified).
// ---------------------------------------------------------------------------
struct WsP { const float* w3; u16* wh; int CO, CI, CIC, NCH, KCd, KCm; };

__global__ void k_wsph(WsP p0, WsP p1)
{
    WsP p = blockIdx.y ? p1 : p0;
    int i = blockIdx.x*blockDim.x + threadIdx.x;
    if (i >= p.CO*p.NCH*p.KCm) return;
    int j = i % p.KCm, t = i / p.KCm;
    int ch = t % p.NCH, co = t / p.NCH;
    float s = 0.f;
    if (j < p.KCd){
        int ci = ch*p.CIC + j/25;
        int uv = j%25, u = uv/5, v = uv%5;
        const float* w = p.w3 + (co*p.CI + ci)*9;
        int pl0 = max(0, u-2), pl1 = min(2, u);
        int q0 = max(0, v-2), q1 = min(2, v);
        for (int pl=pl0; pl<=pl1; ++pl)
            for (int q=q0; q<=q1; ++q) s += w[pl*3+q];
        s *= (1.0f/9.0f);
    }
    p.wh[i] = f2h(s);
}

struct WdP { const float* w; u16* wh; int CO, CI, CIC, NCH, KPQ, KCd, KCm; };

__global__ void k_wdir(WdP p0, WdP p1, WdP p2, WdP p3)
{
    WdP p = (blockIdx.y==0)?p0 : (blockIdx.y==1)?p1 : (blockIdx.y==2)?p2 : p3;
    int i = blockIdx.x*blockDim.x + threadIdx.x;
    if (i >= p.CO*p.NCH*p.KCm) return;
    int j = i % p.KCm, t = i / p.KCm;
    int ch = t % p.NCH, co = t / p.NCH;
    float s = 0.f;
    if (j < p.KCd){
        int ci = ch*p.CIC + j/p.KPQ;
        int r2 = j % p.KPQ;
        s = p.w[(size_t)(co*p.CI + ci)*p.KPQ + r2];
    }
    p.wh[i] = f2h(s);
}

// ---------------------------------------------------------------------------
// Direct MFMA conv engine on a dense u16 image (all 6 layers; sphere layers
// run on materialized xu). Staging is n-fast: lanes = consecutive output
// positions at (wave-uniform) k -> row-local global reads (~4 lines/wave),
// index math is ~8 VALU/lane, NO table lookups (R10/R12 lesson: kill the
// dependent index->gather chain). One barrier pair per K-chunk.
// Fragment layout (guide §3, m89-verified): A/B lane&15 = M/N, k=(lane>>4)*8+j;
// D col=lane&15, row=(lane>>4)*4+reg.
// ---------------------------------------------------------------------------
template<int CO,int OW,int NTOT,int NB,int BSTRIDE,int IH,int IW,
         int KH,int KW,int S,int KPQ,int CIC,
         int NCH,int KCd,int KCm,int KCp,int NT_N,int NT_CO>
__global__ __launch_bounds__(256) void k_dconv(
    const u16* __restrict__ in, const u16* __restrict__ wh,
    const float* __restrict__ bg, const float* __restrict__ bb,
    const float* __restrict__ bm, const float* __restrict__ bv,
    u16* __restrict__ out)
{
    constexpr int NPAD = NT_N*16;
    constexpr int TPW  = (NT_N*NT_CO)/4;
    static_assert((NT_N*NT_CO) % 4 == 0, "tiles split across 4 waves");
    static_assert(KCd == CIC*KPQ, "chunk = whole channels");
    static_assert(KCd % 2 == 0 && KCm % 32 == 0 && KCp % 8 == 0, "tiling");
    static_assert((NPAD & (NPAD-1)) == 0, "NPAD pow2");
    __shared__ __align__(16) u16 sA[NPAD*KCp];
    __shared__ __align__(16) u16 sB[CO*KCp];

    int b  = blockIdx.x / NB;
    int n0 = (blockIdx.x % NB)*NPAD;
    int tid = threadIdx.x;
    const u16* xb = in + (size_t)b*BSTRIDE;

    if constexpr (KCm > KCd){
        constexpr int PADW = KCm - KCd;
        for (int e = tid; e < NPAD*PADW; e += 256)
            sA[(e/PADW)*KCp + KCd + e%PADW] = 0;
    }

    int w = tid >> 6, lane = tid & 63, l15 = lane & 15, l4 = lane >> 4;
    int nt = w % NT_N;
    f32x4 acc[TPW];
    #pragma unroll
    for (int j=0;j<TPW;++j) acc[j] = (f32x4){0.f,0.f,0.f,0.f};

    for (int ch = 0; ch < NCH; ++ch){
        if (ch) __syncthreads();
        const u16* xc = xb + (size_t)ch*CIC*IH*IW;
        // stage A: n-fast im2col (2 adjacent k per thread -> u32 write)
        constexpr int HKD = KCd/2;
        for (int i = tid; i < NPAD*HKD; i += 256){
            int n_l = i & (NPAD-1);
            int k0  = (i/NPAD)*2;
            int n_g = min(n0 + n_l, NTOT-1);
            int oh = n_g/OW, ow = n_g - oh*OW;
            int base = (oh*S)*IW + ow*S;
            int c0 = k0/KPQ, r0 = k0 - c0*KPQ, u0 = r0/KW, v0 = r0 - u0*KW;
            int k1 = k0+1;
            int c1 = k1/KPQ, r1 = k1 - c1*KPQ, u1 = r1/KW, v1 = r1 - u1*KW;
            u16 a0 = xc[(c0*IH + u0)*IW + base + v0];
            u16 a1 = xc[(c1*IH + u1)*IW + base + v1];
            *reinterpret_cast<u32*>(&sA[n_l*KCp + k0]) = (u32)a0 | ((u32)a1 << 16);
        }
        // stage B: weights (16B copies)
        constexpr int W8 = KCm/8;
        for (int i = tid; i < CO*W8; i += 256){
            int co = i / W8, j = (i - co*W8)*8;
            uint4 v = *reinterpret_cast<const uint4*>(wh + ((size_t)co*NCH + ch)*KCm + j);
            *reinterpret_cast<uint4*>(&sB[co*KCp + j]) = v;
        }
        __syncthreads();
        // MFMA
        #pragma unroll
        for (int ks = 0; ks < KCm/32; ++ks){
            half8 a = *reinterpret_cast<const half8*>(&sA[(nt*16 + l15)*KCp + ks*32 + l4*8]);
            #pragma unroll
            for (int j=0;j<TPW;++j){
                int ct = (w + j*4)/NT_N;
                half8 bf = *reinterpret_cast<const half8*>(&sB[(ct*16 + l15)*KCp + ks*32 + l4*8]);
                acc[j] = __builtin_amdgcn_mfma_f32_16x16x32_f16(a, bf, acc[j], 0, 0, 0);
            }
        }
    }
    // epilogue: BN + lrelu, flat [b][co][NTOT] f16
    #pragma unroll
    for (int j=0;j<TPW;++j){
        int ct = (w + j*4)/NT_N;
        int co = ct*16 + l15;
        float inv = bg[co]*rsqrtf(bv[co]+1e-5f);
        float shv = bb[co] - bm[co]*inv;
        size_t ob = (size_t)(b*CO + co)*NTOT;
        #pragma unroll
        for (int r=0;r<4;++r){
            int gn = n0 + nt*16 + l4*4 + r;
            if (gn < NTOT) out[ob + gn] = f2h(lrelu_f(fmaf(acc[j][r], inv, shv)));
        }
    }
}

// ---------------------------------------------------------------------------
// fused = lrelu(h5_flat @ proj_w.T + v @ vproj_w.T + vproj_b)   (h5 is f16)
// ---------------------------------------------------------------------------
__global__ __launch_bounds__(256) void k_head(
    const u16* __restrict__ h5, const float* __restrict__ vin,
    const float* __restrict__ proj_w, const float* __restrict__ vproj_w,
    const float* __restrict__ vproj_b, float* __restrict__ fused)
{
    __shared__ __align__(16) float sh[2560];
    __shared__ float sv[9];
    int b = blockIdx.x, tid = threadIdx.x;
    for (int i = tid; i < 2560; i += 256) sh[i] = h2f(h5[(size_t)b*2560 + i]);
    if (tid < 9) sv[tid] = vin[b*9 + tid];
    __syncthreads();
    const float* pw = proj_w + (size_t)tid*2560;
    float acc = 0.f;
    for (int k=0;k<2560;k+=4){
        float4 s4 = *reinterpret_cast<const float4*>(sh+k);
        float4 w4 = *reinterpret_cast<const float4*>(pw+k);
        acc = fmaf(s4.x,w4.x, fmaf(s4.y,w4.y, fmaf(s4.z,w4.z, fmaf(s4.w,w4.w, acc))));
    }
    float av = 0.f;
    #pragma unroll
    for (int k=0;k<9;++k) av += sv[k]*vproj_w[tid*9+k];
    fused[b*256+tid] = lrelu_f(acc + av + vproj_b[tid]);
}

// ---------------------------------------------------------------------------
// GRU cell
// ---------------------------------------------------------------------------
__global__ __launch_bounds__(256) void k_gru(
    const float* __restrict__ fused, const float* __restrict__ hx,
    const float* __restrict__ wih, const float* __restrict__ whh,
    const float* __restrict__ bih, const float* __restrict__ bhh,
    float* __restrict__ hx_new)
{
    __shared__ __align__(16) float sf[256];
    __shared__ __align__(16) float shx[256];
    int b = blockIdx.x, j = threadIdx.x;
    sf[j]  = fused[b*256+j];
    shx[j] = hx[b*256+j];
    __syncthreads();
    float ga[3], gb[3];
    #pragma unroll
    for (int gi=0; gi<3; ++gi){
        const float* wi = wih + ((size_t)gi*256 + j)*256;
        const float* wh = whh + ((size_t)gi*256 + j)*256;
        float a = 0.f, c = 0.f;
        for (int k=0;k<256;k+=4){
            float4 f4  = *reinterpret_cast<const float4*>(sf+k);
            float4 h4  = *reinterpret_cast<const float4*>(shx+k);
            float4 wi4 = *reinterpret_cast<const float4*>(wi+k);
            float4 wh4 = *reinterpret_cast<const float4*>(wh+k);
            a = fmaf(f4.x,wi4.x, fmaf(f4.y,wi4.y, fmaf(f4.z,wi4.z, fmaf(f4.w,wi4.w, a))));
            c = fmaf(h4.x,wh4.x, fmaf(h4.y,wh4.y, fmaf(h4.z,wh4.z, fmaf(h4.w,wh4.w, c))));
        }
        ga[gi] = a + bih[gi*256+j];
        gb[gi] = c + bhh[gi*256+j];
    }
    float r = 1.f/(1.f+expf(-(ga[0]+gb[0])));
    float z = 1.f/(1.f+expf(-(ga[1]+gb[1])));
    float n = tanhf(ga[2] + r*gb[2]);
    hx_new[b*256+j] = (1.f-z)*n + z*shx[j];
}

// act = lrelu(hx_new) @ fc_w.T
__global__ void k_act(const float* __restrict__ hx_new, const float* __restrict__ fc_w,
                      float* __restrict__ act)
{
    int t = blockIdx.x*blockDim.x + threadIdx.x;
    if (t >= 1024) return;
    int b = t >> 2, o = t & 3;
    const float* h = hx_new + b*256;
    const float* w = fc_w + o*256;
    float acc = 0.f;
    for (int k=0;k<256;++k) acc = fmaf(lrelu_f(h[k]), w[k], acc);
    act[t] = acc;
}

extern "C" void kernel_launch(void* const* d_in, const int* in_sizes, int n_in,
                              void* d_out, int out_size, void* d_ws, size_t ws_size,
                              hipStream_t stream)
{
    const float* x      = (const float*)d_in[0];
    const float* vin    = (const float*)d_in[1];
    const float* hx     = (const float*)d_in[2];
    const float* sc0_w  = (const float*)d_in[3];
    const float* bn0g   = (const float*)d_in[4];
    const float* bn0b   = (const float*)d_in[5];
    const float* bn0m   = (const float*)d_in[6];
    const float* bn0v   = (const float*)d_in[7];
    const float* sc1_w  = (const float*)d_in[8];
    const float* bn1g   = (const float*)d_in[9];
    const float* bn1b   = (const float*)d_in[10];
    const float* bn1m   = (const float*)d_in[11];
    const float* bn1v   = (const float*)d_in[12];
    const float* c2_w   = (const float*)d_in[13];
    const float* bn2g   = (const float*)d_in[14];
    const float* bn2b   = (const float*)d_in[15];
    const float* bn2m   = (const float*)d_in[16];
    const float* bn2v   = (const float*)d_in[17];
    const float* c3_w   = (const float*)d_in[18];
    const float* bn3g   = (const float*)d_in[19];
    const float* bn3b   = (const float*)d_in[20];
    const float* bn3m   = (const float*)d_in[21];
    const float* bn3v   = (const float*)d_in[22];
    const float* c4_w   = (const float*)d_in[23];
    const float* bn4g   = (const float*)d_in[24];
    const float* bn4b   = (const float*)d_in[25];
    const float* bn4m   = (const float*)d_in[26];
    const float* bn4v   = (const float*)d_in[27];
    const float* c5_w   = (const float*)d_in[28];
    const float* bn5g   = (const float*)d_in[29];
    const float* bn5b   = (const float*)d_in[30];
    const float* bn5m   = (const float*)d_in[31];
    const float* bn5v   = (const float*)d_in[32];
    const float* proj_w = (const float*)d_in[33];
    const float* vproj_w= (const float*)d_in[34];
    const float* vproj_b= (const float*)d_in[35];
    const float* gru_wih= (const float*)d_in[36];
    const float* gru_whh= (const float*)d_in[37];
    const float* gru_bih= (const float*)d_in[38];
    const float* gru_bhh= (const float*)d_in[39];
    const float* fc_w   = (const float*)d_in[40];

    char* base = (char*)d_ws;
    size_t off = 0;
    auto alloc = [&](size_t bytes)->char*{
        char* p = base + off; off += (bytes + 255) & ~(size_t)255; return p;
    };
    int* map0 = (int*)alloc((size_t)96*192*4);          // xu0 raster map
    int* map1 = (int*)alloc((size_t)48*96*4);           // xu1 raster map
    u16* wb0  = (u16*)alloc((size_t)32*1*160*2);
    u16* wb1  = (u16*)alloc((size_t)64*4*224*2);
    u16* wb2  = (u16*)alloc((size_t)64*4*160*2);
    u16* wb3  = (u16*)alloc((size_t)64*2*128*2);
    u16* wb4  = (u16*)alloc((size_t)128*4*160*2);
    u16* wb5  = (u16*)alloc((size_t)128*8*160*2);
    // xu0 (56.6MB) is dead before xu1 (75.5MB) is built -> share one region
    u16* xu   = (u16*)alloc((size_t)256*32*48*96*2);    // max(xu0, xu1)
    u16* h0   = (u16*)alloc((size_t)256*32*1953*2);
    u16* h1   = (u16*)alloc((size_t)256*64*465*2);
    u16* h2   = (u16*)alloc((size_t)256*64*377*2);
    u16* h3   = (u16*)alloc((size_t)256*64*84*2);
    u16* h4   = (u16*)alloc((size_t)256*128*48*2);
    u16* h5   = (u16*)alloc((size_t)256*128*20*2);
    float* fused = (float*)alloc((size_t)65536*4);

    // ---- one-time precompute ----
    MapP m0 = { map0, 64, 128, 64, 96*192 };
    MapP m1 = { map1, 31,  63, 32, 48*96 };
    k_map2<<<dim3((96*192+255)/256, 2), 256, 0, stream>>>(m0, m1);
    WsP s0 = { sc0_w, wb0, 32,  6,  6, 1, 150, 160 };
    WsP s1 = { sc1_w, wb1, 64, 32,  8, 4, 200, 224 };
    k_wsph<<<dim3((64*4*224+255)/256, 2), 256, 0, stream>>>(s0, s1);
    WdP d2 = { c2_w, wb2,  64,  64, 16, 4, 9, 144, 160 };
    WdP d3 = { c3_w, wb3,  64,  64, 32, 2, 4, 128, 128 };
    WdP d4 = { c4_w, wb4, 128,  64, 16, 4, 9, 144, 160 };
    WdP d5 = { c5_w, wb5, 128, 128, 16, 8, 9, 144, 160 };
    k_wdir<<<dim3((128*8*160+255)/256, 4), 256, 0, stream>>>(d2, d3, d4, d5);

    // ---- backbone: materialize xu -> direct MFMA conv ----
    // k_dconv<CO,OW,NTOT,NB,BSTRIDE,IH,IW,KH,KW,S,KPQ,CIC,NCH,KCd,KCm,KCp,NT_N,NT_CO>
    k_xu<float><<<dim3(72, 256*6), 256, 0, stream>>>(x, map0, xu, 96*192, 64*128);
    k_dconv<32,63,1953,31,110592,96,192, 5,5,3,25,6, 1,150,160,168,4,2>
        <<<256*31, 256, 0, stream>>>(xu, wb0, bn0g,bn0b,bn0m,bn0v, h0);
    k_xu<u16><<<dim3(18, 256*32), 256, 0, stream>>>(h0, map1, xu, 48*96, 1953);
    k_dconv<64,31,465,15,147456,48,96, 5,5,3,25,8, 4,200,224,232,2,4>
        <<<256*15, 256, 0, stream>>>(xu, wb1, bn1g,bn1b,bn1m,bn1v, h1);
    k_dconv<64,29,377,12,29760,15,31, 3,3,1,9,16, 4,144,160,168,2,4>
        <<<256*12, 256, 0, stream>>>(h1, wb2, bn2g,bn2b,bn2m,bn2v, h2);
    k_dconv<64,14,84,3,24128,13,29, 2,2,2,4,32, 2,128,128,136,2,4>
        <<<256*3,  256, 0, stream>>>(h2, wb3, bn3g,bn3b,bn3m,bn3v, h3);
    k_dconv<128,12,48,3,5376,6,14, 3,3,1,9,16, 4,144,160,168,1,8>
        <<<256*3,  256, 0, stream>>>(h3, wb4, bn4g,bn4b,bn4m,bn4v, h4);
    k_dconv<128,10,20,2,6144,4,12, 3,3,1,9,16, 8,144,160,168,1,8>
        <<<256*2,  256, 0, stream>>>(h4, wb5, bn5g,bn5b,bn5m,bn5v, h5);

    // ---- head ----
    k_head<<<256, 256, 0, stream>>>(h5, vin, proj_w, vproj_w, vproj_b, fused);
    float* outp = (float*)d_out;
    k_gru<<<256, 256, 0, stream>>>(fused, hx, gru_wih, gru_whh, gru_bih, gru_bhh, outp + 1024);
    k_act<<<4, 256, 0, stream>>>(outp + 1024, fc_w, outp);
}

// Round 15
// 407.686 us; speedup vs baseline: 1.7924x; 1.6307x over previous
//
#include <hip/hip_runtime.h>
#include <math.h>

typedef unsigned short u16;
typedef unsigned int   u32;
typedef __attribute__((ext_vector_type(8))) _Float16 half8;
typedef __attribute__((ext_vector_type(4))) float    f32x4;

#define PI_F 3.14159265358979323846f

__device__ __forceinline__ float lrelu_f(float x){ return x >= 0.f ? x : 0.05f*x; }
__device__ __forceinline__ u16 f2h(float f){ _Float16 h = (_Float16)f; u16 u; __builtin_memcpy(&u,&h,2); return u; }
__device__ __forceinline__ float h2f(u16 u){ _Float16 h; __builtin_memcpy(&h,&u,2); return (float)h; }

// ---------------------------------------------------------------------------
// Index map in xu RASTER order (flat = oh*(Wo*9)+ow*9+kh*3+kw, the C-order
// reshape — R0-proven body; R9 lesson: never decode blockwise).
// ---------------------------------------------------------------------------
struct MapP { int* map; int H, W, Wo, total; };

__global__ void k_map2(MapP p0, MapP p1)
{
    MapP p = blockIdx.y ? p1 : p0;
    int i = blockIdx.x*blockDim.x + threadIdx.x;
    if (i >= p.total) return;
    int oh  = i / (p.Wo*9);
    int rem = i % (p.Wo*9);
    int ow  = rem / 9;
    int r2  = rem % 9;
    int kh  = r2/3, kw = r2%3;
    int ihc = min(oh*2, p.H-1);
    int lat = min(max(ihc + kh - 1, 0), p.H-1);
    float phi = ((float)lat + 0.5f)/(float)p.H * PI_F - 0.5f*PI_F;
    float ca  = fmaxf(fabsf(cosf(phi)), 1e-3f);
    float d   = fminf(0.8f/ca, 4.0f);
    float jw  = (float)((ow*2) % p.W);
    float lonf = rintf(jw + d*(float)(kw-1));   // np.round == rint (half-even)
    int lon = (int)lonf % p.W; if (lon < 0) lon += p.W;
    p.map[i] = lat*p.W + lon;
}

// ---------------------------------------------------------------------------
// xu0: NCHW fp32 x -> NHWC u16 [b][pos(96x192)][8] (ch 6,7 zero-padded).
// ---------------------------------------------------------------------------
__global__ void k_xu0(const float* __restrict__ x, const int* __restrict__ map,
                      u16* __restrict__ out)
{
    int p = blockIdx.x*blockDim.x + threadIdx.x;   // 0..18431
    int b = blockIdx.y;
    int m = map[p];
    const float* xb = x + (size_t)b*6*8192 + m;
    u16 v[8];
    #pragma unroll
    for (int c=0;c<6;++c) v[c] = f2h(xb[c*8192]);
    v[6]=0; v[7]=0;
    *reinterpret_cast<uint4*>(out + ((size_t)b*18432 + p)*8) =
        *reinterpret_cast<uint4*>(v);
}

// xu1: NHWC h0 [b][1953][32] -> NHWC xu1 [b][pos(48x96)][32], 16B vectorized.
__global__ void k_xu1(const u16* __restrict__ h0, const int* __restrict__ map,
                      u16* __restrict__ out)
{
    int i = blockIdx.x*blockDim.x + threadIdx.x;   // 0..18431 = pos*4+civ
    int b = blockIdx.y;
    int p = i >> 2, civ = i & 3;
    int m = map[p];
    uint4 v = *reinterpret_cast<const uint4*>(h0 + ((size_t)b*1953 + m)*32 + civ*8);
    *reinterpret_cast<uint4*>(out + ((size_t)b*4608 + p)*32 + civ*8) = v;
}

// ---------------------------------------------------------------------------
// Weights, NHWC-k chunked layout [co][ch][KCm], k-within-chunk = tl*CIP + ci
// (channel-fastest). Pad cols (j>=KCd) and pad channels (ci>=CI) are zero ->
// inert in MFMA. Sphere: fold avg_pool3(conv3x3) -> 5x5/stride3 (R4-verified).
// ---------------------------------------------------------------------------
struct WsP { const float* w3; u16* wh; int CO, CI, CIP, TPC, NCH, KCd, KCm, total; };

__global__ void k_wsph(WsP p0, WsP p1)
{
    WsP p = blockIdx.y ? p1 : p0;
    int i = blockIdx.x*blockDim.x + threadIdx.x;
    if (i >= p.total) return;
    int j = i % p.KCm, t = i / p.KCm;
    int ch = t % p.NCH, co = t / p.NCH;
    float s = 0.f;
    if (j < p.KCd){
        int tl = j / p.CIP, ci = j % p.CIP;
        if (ci < p.CI){
            int tap = ch*p.TPC + tl;
            int u = tap/5, v = tap%5;
            const float* w = p.w3 + (co*p.CI + ci)*9;
            int pl0 = max(0, u-2), pl1 = min(2, u);
            int q0 = max(0, v-2), q1 = min(2, v);
            for (int pl=pl0; pl<=pl1; ++pl)
                for (int q=q0; q<=q1; ++q) s += w[pl*3+q];
            s *= (1.0f/9.0f);
        }
    }
    p.wh[i] = f2h(s);
}

struct WdP { const float* w; u16* wh; int CO, CI, TPC, NCH, KPQ, KCm, total; };

__global__ void k_wdir(WdP p0, WdP p1, WdP p2, WdP p3)
{
    WdP p = (blockIdx.y==0)?p0 : (blockIdx.y==1)?p1 : (blockIdx.y==2)?p2 : p3;
    int i = blockIdx.x*blockDim.x + threadIdx.x;
    if (i >= p.total) return;
    int j = i % p.KCm, t = i / p.KCm;
    int ch = t % p.NCH, co = t / p.NCH;
    int tl = j / p.CI, ci = j % p.CI;
    int tap = ch*p.TPC + tl;
    p.wh[i] = f2h(p.w[(size_t)(co*p.CI + ci)*p.KPQ + tap]);
}

// ---------------------------------------------------------------------------
// NHWC MFMA conv engine (R14 post-mortem: NCHW staging was stuck at 2B/lane
// VMEM + per-lane k-decode across 4 structural rewrites; NHWC makes each
// kernel-tap row CI contiguous u16 -> staging = uint4 copies, no k-decode,
// and the epilogue write is coalesced in co).
// k order within chunk: tl*CI + ci. One barrier pair per chunk.
// Fragment layout (guide §3, m89-verified): A/B lane&15 = M/N, k=(lane>>4)*8+j;
// D col=lane&15 (-> co), row=(lane>>4)*4+reg (-> n).
// ---------------------------------------------------------------------------
template<int CO,int OW,int NTOT,int NB,int IH,int IW,int KW,int S,int CI,
         int TPC,int NCH,int KCm,int KCp,int NT_N,int NT_CO>
__global__ __launch_bounds__(256) void k_nconv(
    const u16* __restrict__ in, const u16* __restrict__ wh,
    const float* __restrict__ bg, const float* __restrict__ bb,
    const float* __restrict__ bm, const float* __restrict__ bv,
    u16* __restrict__ out)
{
    constexpr int NPAD = NT_N*16;
    constexpr int TPW  = (NT_N*NT_CO)/4;
    constexpr int KCd  = TPC*CI;
    constexpr int CIV  = CI/8;
    static_assert((NT_N*NT_CO) % 4 == 0, "tiles split across 4 waves");
    static_assert(CI % 8 == 0, "16B staging vectors");
    static_assert(KCm % 32 == 0 && KCp % 8 == 0 && KCd <= KCm, "tiling");
    static_assert((NPAD & (NPAD-1)) == 0, "NPAD pow2");
    __shared__ __align__(16) u16 sA[NPAD*KCp];
    __shared__ __align__(16) u16 sB[CO*KCp];

    int b  = blockIdx.x / NB;
    int n0 = (blockIdx.x % NB)*NPAD;
    int tid = threadIdx.x;
    const u16* xb = in + (size_t)b*IH*IW*CI;

    if constexpr (KCm > KCd){
        constexpr int PADW = KCm - KCd;
        for (int e = tid; e < NPAD*PADW; e += 256)
            sA[(e/PADW)*KCp + KCd + e%PADW] = 0;
    }

    int w = tid >> 6, lane = tid & 63, l15 = lane & 15, l4 = lane >> 4;
    int nt = w % NT_N;
    f32x4 acc[TPW];
    #pragma unroll
    for (int j=0;j<TPW;++j) acc[j] = (f32x4){0.f,0.f,0.f,0.f};

    for (int ch = 0; ch < NCH; ++ch){
        if (ch) __syncthreads();
        // stage A: per (n, tap, ch-vec8) one 16B copy; tap row is contiguous
        constexpr int ITER = NPAD*TPC*CIV;
        for (int i = tid; i < ITER; i += 256){
            int n_l = i / (TPC*CIV);
            int r   = i - n_l*(TPC*CIV);
            int tl  = r / CIV;
            int civ = r - tl*CIV;
            int n_g = min(n0 + n_l, NTOT-1);
            int oh = n_g/OW, ow = n_g - oh*OW;
            int tap = ch*TPC + tl;
            int u = tap/KW, v = tap - u*KW;
            int pos = (oh*S + u)*IW + ow*S + v;
            uint4 val = *reinterpret_cast<const uint4*>(xb + (size_t)pos*CI + civ*8);
            *reinterpret_cast<uint4*>(&sA[n_l*KCp + tl*CI + civ*8]) = val;
        }
        // stage B: weights (16B copies)
        constexpr int W8 = KCm/8;
        for (int i = tid; i < CO*W8; i += 256){
            int co = i / W8, j = (i - co*W8)*8;
            uint4 v = *reinterpret_cast<const uint4*>(wh + ((size_t)co*NCH + ch)*KCm + j);
            *reinterpret_cast<uint4*>(&sB[co*KCp + j]) = v;
        }
        __syncthreads();
        // MFMA
        #pragma unroll
        for (int ks = 0; ks < KCm/32; ++ks){
            half8 a = *reinterpret_cast<const half8*>(&sA[(nt*16 + l15)*KCp + ks*32 + l4*8]);
            #pragma unroll
            for (int j=0;j<TPW;++j){
                int ct = (w + j*4)/NT_N;
                half8 bf = *reinterpret_cast<const half8*>(&sB[(ct*16 + l15)*KCp + ks*32 + l4*8]);
                acc[j] = __builtin_amdgcn_mfma_f32_16x16x32_f16(a, bf, acc[j], 0, 0, 0);
            }
        }
    }
    // epilogue: BN + lrelu, NHWC [b][n][co] (lanes -> consecutive co: coalesced)
    #pragma unroll
    for (int j=0;j<TPW;++j){
        int ct = (w + j*4)/NT_N;
        int co = ct*16 + l15;
        float inv = bg[co]*rsqrtf(bv[co]+1e-5f);
        float shv = bb[co] - bm[co]*inv;
        #pragma unroll
        for (int r=0;r<4;++r){
            int gn = n0 + nt*16 + l4*4 + r;
            if (gn < NTOT)
                out[((size_t)b*NTOT + gn)*CO + co] = f2h(lrelu_f(fmaf(acc[j][r], inv, shv)));
        }
    }
}

// ---------------------------------------------------------------------------
// fused = lrelu(h5_flat @ proj_w.T + v @ vproj_w.T + vproj_b)
// h5 is NHWC [b][20][128]; reference flatten is co-major: k_ref = co*20 + n.
// ---------------------------------------------------------------------------
__global__ __launch_bounds__(256) void k_head(
    const u16* __restrict__ h5, const float* __restrict__ vin,
    const float* __restrict__ proj_w, const float* __restrict__ vproj_w,
    const float* __restrict__ vproj_b, float* __restrict__ fused)
{
    __shared__ __align__(16) float sh[2560];
    __shared__ float sv[9];
    int b = blockIdx.x, tid = threadIdx.x;
    for (int i = tid; i < 2560; i += 256){
        int co = i / 20, n = i - co*20;
        sh[i] = h2f(h5[((size_t)b*20 + n)*128 + co]);
    }
    if (tid < 9) sv[tid] = vin[b*9 + tid];
    __syncthreads();
    const float* pw = proj_w + (size_t)tid*2560;
    float acc = 0.f;
    for (int k=0;k<2560;k+=4){
        float4 s4 = *reinterpret_cast<const float4*>(sh+k);
        float4 w4 = *reinterpret_cast<const float4*>(pw+k);
        acc = fmaf(s4.x,w4.x, fmaf(s4.y,w4.y, fmaf(s4.z,w4.z, fmaf(s4.w,w4.w, acc))));
    }
    float av = 0.f;
    #pragma unroll
    for (int k=0;k<9;++k) av += sv[k]*vproj_w[tid*9+k];
    fused[b*256+tid] = lrelu_f(acc + av + vproj_b[tid]);
}

// ---------------------------------------------------------------------------
// GRU cell
// ---------------------------------------------------------------------------
__global__ __launch_bounds__(256) void k_gru(
    const float* __restrict__ fused, const float* __restrict__ hx,
    const float* __restrict__ wih, const float* __restrict__ whh,
    const float* __restrict__ bih, const float* __restrict__ bhh,
    float* __restrict__ hx_new)
{
    __shared__ __align__(16) float sf[256];
    __shared__ __align__(16) float shx[256];
    int b = blockIdx.x, j = threadIdx.x;
    sf[j]  = fused[b*256+j];
    shx[j] = hx[b*256+j];
    __syncthreads();
    float ga[3], gb[3];
    #pragma unroll
    for (int gi=0; gi<3; ++gi){
        const float* wi = wih + ((size_t)gi*256 + j)*256;
        const float* wh = whh + ((size_t)gi*256 + j)*256;
        float a = 0.f, c = 0.f;
        for (int k=0;k<256;k+=4){
            float4 f4  = *reinterpret_cast<const float4*>(sf+k);
            float4 h4  = *reinterpret_cast<const float4*>(shx+k);
            float4 wi4 = *reinterpret_cast<const float4*>(wi+k);
            float4 wh4 = *reinterpret_cast<const float4*>(wh+k);
            a = fmaf(f4.x,wi4.x, fmaf(f4.y,wi4.y, fmaf(f4.z,wi4.z, fmaf(f4.w,wi4.w, a))));
            c = fmaf(h4.x,wh4.x, fmaf(h4.y,wh4.y, fmaf(h4.z,wh4.z, fmaf(h4.w,wh4.w, c))));
        }
        ga[gi] = a + bih[gi*256+j];
        gb[gi] = c + bhh[gi*256+j];
    }
    float r = 1.f/(1.f+expf(-(ga[0]+gb[0])));
    float z = 1.f/(1.f+expf(-(ga[1]+gb[1])));
    float n = tanhf(ga[2] + r*gb[2]);
    hx_new[b*256+j] = (1.f-z)*n + z*shx[j];
}

// act = lrelu(hx_new) @ fc_w.T
__global__ void k_act(const float* __restrict__ hx_new, const float* __restrict__ fc_w,
                      float* __restrict__ act)
{
    int t = blockIdx.x*blockDim.x + threadIdx.x;
    if (t >= 1024) return;
    int b = t >> 2, o = t & 3;
    const float* h = hx_new + b*256;
    const float* w = fc_w + o*256;
    float acc = 0.f;
    for (int k=0;k<256;++k) acc = fmaf(lrelu_f(h[k]), w[k], acc);
    act[t] = acc;
}

extern "C" void kernel_launch(void* const* d_in, const int* in_sizes, int n_in,
                              void* d_out, int out_size, void* d_ws, size_t ws_size,
                              hipStream_t stream)
{
    const float* x      = (const float*)d_in[0];
    const float* vin    = (const float*)d_in[1];
    const float* hx     = (const float*)d_in[2];
    const float* sc0_w  = (const float*)d_in[3];
    const float* bn0g   = (const float*)d_in[4];
    const float* bn0b   = (const float*)d_in[5];
    const float* bn0m   = (const float*)d_in[6];
    const float* bn0v   = (const float*)d_in[7];
    const float* sc1_w  = (const float*)d_in[8];
    const float* bn1g   = (const float*)d_in[9];
    const float* bn1b   = (const float*)d_in[10];
    const float* bn1m   = (const float*)d_in[11];
    const float* bn1v   = (const float*)d_in[12];
    const float* c2_w   = (const float*)d_in[13];
    const float* bn2g   = (const float*)d_in[14];
    const float* bn2b   = (const float*)d_in[15];
    const float* bn2m   = (const float*)d_in[16];
    const float* bn2v   = (const float*)d_in[17];
    const float* c3_w   = (const float*)d_in[18];
    const float* bn3g   = (const float*)d_in[19];
    const float* bn3b   = (const float*)d_in[20];
    const float* bn3m   = (const float*)d_in[21];
    const float* bn3v   = (const float*)d_in[22];
    const float* c4_w   = (const float*)d_in[23];
    const float* bn4g   = (const float*)d_in[24];
    const float* bn4b   = (const float*)d_in[25];
    const float* bn4m   = (const float*)d_in[26];
    const float* bn4v   = (const float*)d_in[27];
    const float* c5_w   = (const float*)d_in[28];
    const float* bn5g   = (const float*)d_in[29];
    const float* bn5b   = (const float*)d_in[30];
    const float* bn5m   = (const float*)d_in[31];
    const float* bn5v   = (const float*)d_in[32];
    const float* proj_w = (const float*)d_in[33];
    const float* vproj_w= (const float*)d_in[34];
    const float* vproj_b= (const float*)d_in[35];
    const float* gru_wih= (const float*)d_in[36];
    const float* gru_whh= (const float*)d_in[37];
    const float* gru_bih= (const float*)d_in[38];
    const float* gru_bhh= (const float*)d_in[39];
    const float* fc_w   = (const float*)d_in[40];

    char* base = (char*)d_ws;
    size_t off = 0;
    auto alloc = [&](size_t bytes)->char*{
        char* p = base + off; off += (bytes + 255) & ~(size_t)255; return p;
    };
    int* map0 = (int*)alloc((size_t)96*192*4);
    int* map1 = (int*)alloc((size_t)48*96*4);
    u16* wb0  = (u16*)alloc((size_t)32*1*224*2);
    u16* wb1  = (u16*)alloc((size_t)64*5*160*2);
    u16* wb2  = (u16*)alloc((size_t)64*3*192*2);
    u16* wb3  = (u16*)alloc((size_t)64*2*128*2);
    u16* wb4  = (u16*)alloc((size_t)128*3*192*2);
    u16* wb5  = (u16*)alloc((size_t)128*9*128*2);
    // xu0 [256][18432][8] and xu1 [256][4608][32] are both 75.5MB and have
    // disjoint lifetimes -> share one region
    u16* xu   = (u16*)alloc((size_t)256*18432*8*2);
    u16* h0   = (u16*)alloc((size_t)256*1953*32*2);
    u16* h1   = (u16*)alloc((size_t)256*465*64*2);
    u16* h2   = (u16*)alloc((size_t)256*377*64*2);
    u16* h3   = (u16*)alloc((size_t)256*84*64*2);
    u16* h4   = (u16*)alloc((size_t)256*48*128*2);
    u16* h5   = (u16*)alloc((size_t)256*20*128*2);
    float* fused = (float*)alloc((size_t)65536*4);

    // ---- one-time precompute ----
    MapP m0 = { map0, 64, 128, 64, 96*192 };
    MapP m1 = { map1, 31,  63, 32, 48*96 };
    k_map2<<<dim3(72, 2), 256, 0, stream>>>(m0, m1);
    WsP s0 = { sc0_w, wb0, 32,  6, 8, 25, 1, 200, 224, 32*1*224 };
    WsP s1 = { sc1_w, wb1, 64, 32, 32, 5, 5, 160, 160, 64*5*160 };
    k_wsph<<<dim3((64*5*160+255)/256, 2), 256, 0, stream>>>(s0, s1);
    WdP d2 = { c2_w, wb2,  64,  64, 3, 3, 9, 192, 64*3*192 };
    WdP d3 = { c3_w, wb3,  64,  64, 2, 2, 4, 128, 64*2*128 };
    WdP d4 = { c4_w, wb4, 128,  64, 3, 3, 9, 192, 128*3*192 };
    WdP d5 = { c5_w, wb5, 128, 128, 1, 9, 9, 128, 128*9*128 };
    k_wdir<<<dim3((128*9*128+255)/256, 4), 256, 0, stream>>>(d2, d3, d4, d5);

    // ---- backbone (NHWC, MFMA f16) ----
    // k_nconv<CO,OW,NTOT,NB,IH,IW,KW,S,CI,TPC,NCH,KCm,KCp,NT_N,NT_CO>
    k_xu0<<<dim3(72, 256), 256, 0, stream>>>(x, map0, xu);
    k_nconv<32,63,1953,31, 96,192, 5,3, 8,25,1, 224,232, 4,2>
        <<<256*31, 256, 0, stream>>>(xu, wb0, bn0g,bn0b,bn0m,bn0v, h0);
    k_xu1<<<dim3(72, 256), 256, 0, stream>>>(h0, map1, xu);
    k_nconv<64,31,465,15, 48,96, 5,3, 32,5,5, 160,168, 2,4>
        <<<256*15, 256, 0, stream>>>(xu, wb1, bn1g,bn1b,bn1m,bn1v, h1);
    k_nconv<64,29,377,12, 15,31, 3,1, 64,3,3, 192,200, 2,4>
        <<<256*12, 256, 0, stream>>>(h1, wb2, bn2g,bn2b,bn2m,bn2v, h2);
    k_nconv<64,14,84,3, 13,29, 2,2, 64,2,2, 128,136, 2,4>
        <<<256*3,  256, 0, stream>>>(h2, wb3, bn3g,bn3b,bn3m,bn3v, h3);
    k_nconv<128,12,48,3, 6,14, 3,1, 64,3,3, 192,200, 1,8>
        <<<256*3,  256, 0, stream>>>(h3, wb4, bn4g,bn4b,bn4m,bn4v, h4);
    k_nconv<128,10,20,2, 4,12, 3,1, 128,1,9, 128,136, 1,8>
        <<<256*2,  256, 0, stream>>>(h4, wb5, bn5g,bn5b,bn5m,bn5v, h5);

    // ---- head ----
    k_head<<<256, 256, 0, stream>>>(h5, vin, proj_w, vproj_w, vproj_b, fused);
    float* outp = (float*)d_out;
    k_gru<<<256, 256, 0, stream>>>(fused, hx, gru_wih, gru_whh, gru_bih, gru_bhh, outp + 1024);
    k_act<<<4, 256, 0, stream>>>(outp + 1024, fc_w, outp);
}

// Round 16
// 343.490 us; speedup vs baseline: 2.1274x; 1.1869x over previous
//
#include <hip/hip_runtime.h>
#include <math.h>

typedef unsigned short u16;
typedef unsigned int   u32;
typedef __attribute__((ext_vector_type(8))) _Float16 half8;
typedef __attribute__((ext_vector_type(4))) float    f32x4;

#define PI_F 3.14159265358979323846f

__device__ __forceinline__ float lrelu_f(float x){ return x >= 0.f ? x : 0.05f*x; }
__device__ __forceinline__ u16 f2h(float f){ _Float16 h = (_Float16)f; u16 u; __builtin_memcpy(&u,&h,2); return u; }
__device__ __forceinline__ float h2f(u16 u){ _Float16 h; __builtin_memcpy(&h,&u,2); return (float)h; }

// ---------------------------------------------------------------------------
// Index map in xu RASTER order (flat = oh*(Wo*9)+ow*9+kh*3+kw, the C-order
// reshape — R0-proven body; R9 lesson: never decode blockwise).
// ---------------------------------------------------------------------------
struct MapP { int* map; int H, W, Wo, total; };

__global__ void k_map2(MapP p0, MapP p1)
{
    MapP p = blockIdx.y ? p1 : p0;
    int i = blockIdx.x*blockDim.x + threadIdx.x;
    if (i >= p.total) return;
    int oh  = i / (p.Wo*9);
    int rem = i % (p.Wo*9);
    int ow  = rem / 9;
    int r2  = rem % 9;
    int kh  = r2/3, kw = r2%3;
    int ihc = min(oh*2, p.H-1);
    int lat = min(max(ihc + kh - 1, 0), p.H-1);
    float phi = ((float)lat + 0.5f)/(float)p.H * PI_F - 0.5f*PI_F;
    float ca  = fmaxf(fabsf(cosf(phi)), 1e-3f);
    float d   = fminf(0.8f/ca, 4.0f);
    float jw  = (float)((ow*2) % p.W);
    float lonf = rintf(jw + d*(float)(kw-1));   // np.round == rint (half-even)
    int lon = (int)lonf % p.W; if (lon < 0) lon += p.W;
    p.map[i] = lat*p.W + lon;
}

// ---------------------------------------------------------------------------
// xu0: NCHW fp32 x -> NHWC u16 [b][pos(96x192)][8] (ch 6,7 zero-padded).
// ---------------------------------------------------------------------------
__global__ void k_xu0(const float* __restrict__ x, const int* __restrict__ map,
                      u16* __restrict__ out)
{
    int p = blockIdx.x*blockDim.x + threadIdx.x;   // 0..18431
    int b = blockIdx.y;
    int m = map[p];
    const float* xb = x + (size_t)b*6*8192 + m;
    u16 v[8];
    #pragma unroll
    for (int c=0;c<6;++c) v[c] = f2h(xb[c*8192]);
    v[6]=0; v[7]=0;
    *reinterpret_cast<uint4*>(out + ((size_t)b*18432 + p)*8) =
        *reinterpret_cast<uint4*>(v);
}

// xu1: NHWC h0 [b][1953][32] -> NHWC xu1 [b][pos(48x96)][32], 16B vectorized.
__global__ void k_xu1(const u16* __restrict__ h0, const int* __restrict__ map,
                      u16* __restrict__ out)
{
    int i = blockIdx.x*blockDim.x + threadIdx.x;   // 0..18431 = pos*4+civ
    int b = blockIdx.y;
    int p = i >> 2, civ = i & 3;
    int m = map[p];
    uint4 v = *reinterpret_cast<const uint4*>(h0 + ((size_t)b*1953 + m)*32 + civ*8);
    *reinterpret_cast<uint4*>(out + ((size_t)b*4608 + p)*32 + civ*8) = v;
}

// ---------------------------------------------------------------------------
// Weights, NHWC-k chunked layout [co][ch][KCm], k-within-chunk = tl*CIP + ci
// (channel-fastest). Pad cols/channels zero -> inert in MFMA.
// Sphere: fold avg_pool3(conv3x3) -> 5x5/stride3 (R4-verified).
// ---------------------------------------------------------------------------
struct WsP { const float* w3; u16* wh; int CO, CI, CIP, TPC, NCH, KCd, KCm, total; };

__global__ void k_wsph(WsP p0, WsP p1)
{
    WsP p = blockIdx.y ? p1 : p0;
    int i = blockIdx.x*blockDim.x + threadIdx.x;
    if (i >= p.total) return;
    int j = i % p.KCm, t = i / p.KCm;
    int ch = t % p.NCH, co = t / p.NCH;
    float s = 0.f;
    if (j < p.KCd){
        int tl = j / p.CIP, ci = j % p.CIP;
        if (ci < p.CI){
            int tap = ch*p.TPC + tl;
            int u = tap/5, v = tap%5;
            const float* w = p.w3 + (co*p.CI + ci)*9;
            int pl0 = max(0, u-2), pl1 = min(2, u);
            int q0 = max(0, v-2), q1 = min(2, v);
            for (int pl=pl0; pl<=pl1; ++pl)
                for (int q=q0; q<=q1; ++q) s += w[pl*3+q];
            s *= (1.0f/9.0f);
        }
    }
    p.wh[i] = f2h(s);
}

struct WdP { const float* w; u16* wh; int CO, CI, TPC, NCH, KPQ, KCm, total; };

__global__ void k_wdir(WdP p0, WdP p1, WdP p2, WdP p3)
{
    WdP p = (blockIdx.y==0)?p0 : (blockIdx.y==1)?p1 : (blockIdx.y==2)?p2 : p3;
    int i = blockIdx.x*blockDim.x + threadIdx.x;
    if (i >= p.total) return;
    int j = i % p.KCm, t = i / p.KCm;
    int ch = t % p.NCH, co = t / p.NCH;
    int tl = j / p.CI, ci = j % p.CI;
    int tap = ch*p.TPC + tl;
    p.wh[i] = f2h(p.w[(size_t)(co*p.CI + ci)*p.KPQ + tap]);
}

// ---------------------------------------------------------------------------
// Head/GRU weight prep (R15 post-mortem: k_head/k_gru were latency-bound
// GEMV kernels at 11% occupancy -> MFMA GEMMs). pwh columns permuted to
// NHWC-flat order: k_nhwc = pos*128+co  <->  k_ref = co*20+pos.
// ---------------------------------------------------------------------------
struct HpP { const float* pw; const float* wih; const float* whh;
             u16* pwh; u16* wihh; u16* whhh; };

__global__ void k_hprep(HpP p)
{
    int i = blockIdx.x*blockDim.x + threadIdx.x;
    int y = blockIdx.y;
    if (y == 0){
        if (i >= 256*2560) return;
        int n = i / 2560, k = i % 2560;
        int pos = k >> 7, co = k & 127;
        p.pwh[i] = f2h(p.pw[(size_t)n*2560 + co*20 + pos]);
    } else if (y == 1){
        if (i >= 768*256) return;
        p.wihh[i] = f2h(p.wih[i]);
    } else {
        if (i >= 768*256) return;
        p.whhh[i] = f2h(p.whh[i]);
    }
}

// ---------------------------------------------------------------------------
// NHWC MFMA conv engine (R15-verified).
// Fragment layout (guide §3, m89-verified): A/B lane&15 = M/N, k=(lane>>4)*8+j;
// D col=lane&15 (-> co), row=(lane>>4)*4+reg (-> n).
// ---------------------------------------------------------------------------
template<int CO,int OW,int NTOT,int NB,int IH,int IW,int KW,int S,int CI,
         int TPC,int NCH,int KCm,int KCp,int NT_N,int NT_CO>
__global__ __launch_bounds__(256) void k_nconv(
    const u16* __restrict__ in, const u16* __restrict__ wh,
    const float* __restrict__ bg, const float* __restrict__ bb,
    const float* __restrict__ bm, const float* __restrict__ bv,
    u16* __restrict__ out)
{
    constexpr int NPAD = NT_N*16;
    constexpr int TPW  = (NT_N*NT_CO)/4;
    constexpr int KCd  = TPC*CI;
    constexpr int CIV  = CI/8;
    static_assert((NT_N*NT_CO) % 4 == 0, "tiles split across 4 waves");
    static_assert(CI % 8 == 0, "16B staging vectors");
    static_assert(KCm % 32 == 0 && KCp % 8 == 0 && KCd <= KCm, "tiling");
    static_assert((NPAD & (NPAD-1)) == 0, "NPAD pow2");
    __shared__ __align__(16) u16 sA[NPAD*KCp];
    __shared__ __align__(16) u16 sB[CO*KCp];

    int b  = blockIdx.x / NB;
    int n0 = (blockIdx.x % NB)*NPAD;
    int tid = threadIdx.x;
    const u16* xb = in + (size_t)b*IH*IW*CI;

    if constexpr (KCm > KCd){
        constexpr int PADW = KCm - KCd;
        for (int e = tid; e < NPAD*PADW; e += 256)
            sA[(e/PADW)*KCp + KCd + e%PADW] = 0;
    }

    int w = tid >> 6, lane = tid & 63, l15 = lane & 15, l4 = lane >> 4;
    int nt = w % NT_N;
    f32x4 acc[TPW];
    #pragma unroll
    for (int j=0;j<TPW;++j) acc[j] = (f32x4){0.f,0.f,0.f,0.f};

    for (int ch = 0; ch < NCH; ++ch){
        if (ch) __syncthreads();
        constexpr int ITER = NPAD*TPC*CIV;
        for (int i = tid; i < ITER; i += 256){
            int n_l = i / (TPC*CIV);
            int r   = i - n_l*(TPC*CIV);
            int tl  = r / CIV;
            int civ = r - tl*CIV;
            int n_g = min(n0 + n_l, NTOT-1);
            int oh = n_g/OW, ow = n_g - oh*OW;
            int tap = ch*TPC + tl;
            int u = tap/KW, v = tap - u*KW;
            int pos = (oh*S + u)*IW + ow*S + v;
            uint4 val = *reinterpret_cast<const uint4*>(xb + (size_t)pos*CI + civ*8);
            *reinterpret_cast<uint4*>(&sA[n_l*KCp + tl*CI + civ*8]) = val;
        }
        constexpr int W8 = KCm/8;
        for (int i = tid; i < CO*W8; i += 256){
            int co = i / W8, j = (i - co*W8)*8;
            uint4 v = *reinterpret_cast<const uint4*>(wh + ((size_t)co*NCH + ch)*KCm + j);
            *reinterpret_cast<uint4*>(&sB[co*KCp + j]) = v;
        }
        __syncthreads();
        #pragma unroll
        for (int ks = 0; ks < KCm/32; ++ks){
            half8 a = *reinterpret_cast<const half8*>(&sA[(nt*16 + l15)*KCp + ks*32 + l4*8]);
            #pragma unroll
            for (int j=0;j<TPW;++j){
                int ct = (w + j*4)/NT_N;
                half8 bf = *reinterpret_cast<const half8*>(&sB[(ct*16 + l15)*KCp + ks*32 + l4*8]);
                acc[j] = __builtin_amdgcn_mfma_f32_16x16x32_f16(a, bf, acc[j], 0, 0, 0);
            }
        }
    }
    #pragma unroll
    for (int j=0;j<TPW;++j){
        int ct = (w + j*4)/NT_N;
        int co = ct*16 + l15;
        float inv = bg[co]*rsqrtf(bv[co]+1e-5f);
        float shv = bb[co] - bm[co]*inv;
        #pragma unroll
        for (int r=0;r<4;++r){
            int gn = n0 + nt*16 + l4*4 + r;
            if (gn < NTOT)
                out[((size_t)b*NTOT + gn)*CO + co] = f2h(lrelu_f(fmaf(acc[j][r], inv, shv)));
        }
    }
}

// ---------------------------------------------------------------------------
// Head GEMM: fused = lrelu(h5flat[256x2560] @ pwh^T + v@vproj^T + vproj_b).
// 64x64 tiles, grid(4,4); wave w = M-16-tile, j = N-16-tile. Output f16.
// ---------------------------------------------------------------------------
__global__ __launch_bounds__(256) void k_head2(
    const u16* __restrict__ h5, const u16* __restrict__ pwh,
    const float* __restrict__ vin, const float* __restrict__ vproj_w,
    const float* __restrict__ vproj_b, u16* __restrict__ fusedh)
{
    __shared__ __align__(16) u16 sA[64*136];
    __shared__ __align__(16) u16 sB[64*136];
    __shared__ float sv[64*9];
    int m0 = blockIdx.x*64, nc0 = blockIdx.y*64;
    int tid = threadIdx.x;
    int w = tid >> 6, lane = tid & 63, l15 = lane & 15, l4 = lane >> 4;
    f32x4 acc[4];
    #pragma unroll
    for (int j=0;j<4;++j) acc[j] = (f32x4){0.f,0.f,0.f,0.f};

    for (int i = tid; i < 576; i += 256) sv[i] = vin[(m0 + i/9)*9 + i%9];

    for (int kc0 = 0; kc0 < 2560; kc0 += 128){
        if (kc0) __syncthreads();
        for (int i = tid; i < 1024; i += 256){
            int r = i >> 4, jv = (i & 15)*8;
            *reinterpret_cast<uint4*>(&sA[r*136 + jv]) =
                *reinterpret_cast<const uint4*>(h5 + (size_t)(m0+r)*2560 + kc0 + jv);
            *reinterpret_cast<uint4*>(&sB[r*136 + jv]) =
                *reinterpret_cast<const uint4*>(pwh + (size_t)(nc0+r)*2560 + kc0 + jv);
        }
        __syncthreads();
        #pragma unroll
        for (int ks = 0; ks < 4; ++ks){
            half8 a = *reinterpret_cast<const half8*>(&sA[(w*16 + l15)*136 + ks*32 + l4*8]);
            #pragma unroll
            for (int j=0;j<4;++j){
                half8 bf = *reinterpret_cast<const half8*>(&sB[(j*16 + l15)*136 + ks*32 + l4*8]);
                acc[j] = __builtin_amdgcn_mfma_f32_16x16x32_f16(a, bf, acc[j], 0, 0, 0);
            }
        }
    }
    #pragma unroll
    for (int j=0;j<4;++j){
        int nc = nc0 + j*16 + l15;
        float bias = vproj_b[nc];
        #pragma unroll
        for (int r=0;r<4;++r){
            int ml = w*16 + l4*4 + r;
            float av = 0.f;
            #pragma unroll
            for (int k=0;k<9;++k) av = fmaf(sv[ml*9+k], vproj_w[nc*9+k], av);
            fusedh[(size_t)(m0+ml)*256 + nc] = f2h(lrelu_f(acc[j][r] + av + bias));
        }
    }
}

// ---------------------------------------------------------------------------
// GRU gate GEMM: gbuf[:,0:768] = fused @ wih^T ; gbuf[:,768:1536] = hx @ whh^T.
// grid(4, 24): y = half*12 + ntile. A is f16 (fused) or fp32 (hx, cvt at stage).
// ---------------------------------------------------------------------------
__global__ __launch_bounds__(256) void k_ggemm(
    const u16* __restrict__ fusedh, const float* __restrict__ hx,
    const u16* __restrict__ wihh, const u16* __restrict__ whhh,
    float* __restrict__ gbuf)
{
    __shared__ __align__(16) u16 sA[64*136];
    __shared__ __align__(16) u16 sB[64*136];
    int m0 = blockIdx.x*64;
    int t  = blockIdx.y;
    int half = t / 12, nt = t - half*12;
    int n0 = nt*64;
    const u16* B = (half ? whhh : wihh) + (size_t)n0*256;
    int tid = threadIdx.x;
    int w = tid >> 6, lane = tid & 63, l15 = lane & 15, l4 = lane >> 4;
    f32x4 acc[4];
    #pragma unroll
    for (int j=0;j<4;++j) acc[j] = (f32x4){0.f,0.f,0.f,0.f};

    for (int kc0 = 0; kc0 < 256; kc0 += 128){
        if (kc0) __syncthreads();
        for (int i = tid; i < 1024; i += 256){
            int r = i >> 4, jv = (i & 15)*8;
            if (half == 0){
                *reinterpret_cast<uint4*>(&sA[r*136 + jv]) =
                    *reinterpret_cast<const uint4*>(fusedh + (size_t)(m0+r)*256 + kc0 + jv);
            } else {
                const float* src = hx + (size_t)(m0+r)*256 + kc0 + jv;
                float4 f0 = *reinterpret_cast<const float4*>(src);
                float4 f1 = *reinterpret_cast<const float4*>(src+4);
                u16 v[8] = { f2h(f0.x),f2h(f0.y),f2h(f0.z),f2h(f0.w),
                             f2h(f1.x),f2h(f1.y),f2h(f1.z),f2h(f1.w) };
                *reinterpret_cast<uint4*>(&sA[r*136 + jv]) = *reinterpret_cast<uint4*>(v);
            }
            *reinterpret_cast<uint4*>(&sB[r*136 + jv]) =
                *reinterpret_cast<const uint4*>(B + (size_t)r*256 + kc0 + jv);
        }
        __syncthreads();
        #pragma unroll
        for (int ks = 0; ks < 4; ++ks){
            half8 a = *reinterpret_cast<const half8*>(&sA[(w*16 + l15)*136 + ks*32 + l4*8]);
            #pragma unroll
            for (int j=0;j<4;++j){
                half8 bf = *reinterpret_cast<const half8*>(&sB[(j*16 + l15)*136 + ks*32 + l4*8]);
                acc[j] = __builtin_amdgcn_mfma_f32_16x16x32_f16(a, bf, acc[j], 0, 0, 0);
            }
        }
    }
    #pragma unroll
    for (int j=0;j<4;++j){
        int nc = half*768 + n0 + j*16 + l15;
        #pragma unroll
        for (int r=0;r<4;++r){
            int m = m0 + w*16 + l4*4 + r;
            gbuf[(size_t)m*1536 + nc] = acc[j][r];
        }
    }
}

// pointwise GRU update
__global__ __launch_bounds__(256) void k_gate(
    const float* __restrict__ gbuf, const float* __restrict__ hx,
    const float* __restrict__ bih, const float* __restrict__ bhh,
    float* __restrict__ hx_new)
{
    int b = blockIdx.x, j = threadIdx.x;
    const float* g = gbuf + (size_t)b*1536;
    float ir = g[j]       + bih[j];
    float iz = g[256+j]   + bih[256+j];
    float in_= g[512+j]   + bih[512+j];
    float hr = g[768+j]   + bhh[j];
    float hz = g[1024+j]  + bhh[256+j];
    float hn = g[1280+j]  + bhh[512+j];
    float r = 1.f/(1.f+expf(-(ir+hr)));
    float z = 1.f/(1.f+expf(-(iz+hz)));
    float n = tanhf(in_ + r*hn);
    hx_new[b*256+j] = (1.f-z)*n + z*hx[b*256+j];
}

// act = lrelu(hx_new) @ fc_w.T
__global__ void k_act(const float* __restrict__ hx_new, const float* __restrict__ fc_w,
                      float* __restrict__ act)
{
    int t = blockIdx.x*blockDim.x + threadIdx.x;
    if (t >= 1024) return;
    int b = t >> 2, o = t & 3;
    const float* h = hx_new + b*256;
    const float* w = fc_w + o*256;
    float acc = 0.f;
    for (int k=0;k<256;++k) acc = fmaf(lrelu_f(h[k]), w[k], acc);
    act[t] = acc;
}

extern "C" void kernel_launch(void* const* d_in, const int* in_sizes, int n_in,
                              void* d_out, int out_size, void* d_ws, size_t ws_size,
                              hipStream_t stream)
{
    const float* x      = (const float*)d_in[0];
    const float* vin    = (const float*)d_in[1];
    const float* hx     = (const float*)d_in[2];
    const float* sc0_w  = (const float*)d_in[3];
    const float* bn0g   = (const float*)d_in[4];
    const float* bn0b   = (const float*)d_in[5];
    const float* bn0m   = (const float*)d_in[6];
    const float* bn0v   = (const float*)d_in[7];
    const float* sc1_w  = (const float*)d_in[8];
    const float* bn1g   = (const float*)d_in[9];
    const float* bn1b   = (const float*)d_in[10];
    const float* bn1m   = (const float*)d_in[11];
    const float* bn1v   = (const float*)d_in[12];
    const float* c2_w   = (const float*)d_in[13];
    const float* bn2g   = (const float*)d_in[14];
    const float* bn2b   = (const float*)d_in[15];
    const float* bn2m   = (const float*)d_in[16];
    const float* bn2v   = (const float*)d_in[17];
    const float* c3_w   = (const float*)d_in[18];
    const float* bn3g   = (const float*)d_in[19];
    const float* bn3b   = (const float*)d_in[20];
    const float* bn3m   = (const float*)d_in[21];
    const float* bn3v   = (const float*)d_in[22];
    const float* c4_w   = (const float*)d_in[23];
    const float* bn4g   = (const float*)d_in[24];
    const float* bn4b   = (const float*)d_in[25];
    const float* bn4m   = (const float*)d_in[26];
    const float* bn4v   = (const float*)d_in[27];
    const float* c5_w   = (const float*)d_in[28];
    const float* bn5g   = (const float*)d_in[29];
    const float* bn5b   = (const float*)d_in[30];
    const float* bn5m   = (const float*)d_in[31];
    const float* bn5v   = (const float*)d_in[32];
    const float* proj_w = (const float*)d_in[33];
    const float* vproj_w= (const float*)d_in[34];
    const float* vproj_b= (const float*)d_in[35];
    const float* gru_wih= (const float*)d_in[36];
    const float* gru_whh= (const float*)d_in[37];
    const float* gru_bih= (const float*)d_in[38];
    const float* gru_bhh= (const float*)d_in[39];
    const float* fc_w   = (const float*)d_in[40];

    char* base = (char*)d_ws;
    size_t off = 0;
    auto alloc = [&](size_t bytes)->char*{
        char* p = base + off; off += (bytes + 255) & ~(size_t)255; return p;
    };
    int* map0 = (int*)alloc((size_t)96*192*4);
    int* map1 = (int*)alloc((size_t)48*96*4);
    u16* wb0  = (u16*)alloc((size_t)32*1*224*2);
    u16* wb1  = (u16*)alloc((size_t)64*5*160*2);
    u16* wb2  = (u16*)alloc((size_t)64*3*192*2);
    u16* wb3  = (u16*)alloc((size_t)64*2*128*2);
    u16* wb4  = (u16*)alloc((size_t)128*3*192*2);
    u16* wb5  = (u16*)alloc((size_t)128*9*128*2);
    u16* pwh  = (u16*)alloc((size_t)256*2560*2);
    u16* wihh = (u16*)alloc((size_t)768*256*2);
    u16* whhh = (u16*)alloc((size_t)768*256*2);
    // xu0 [256][18432][8] and xu1 [256][4608][32] are both 75.5MB, disjoint
    // lifetimes -> share one region
    u16* xu   = (u16*)alloc((size_t)256*18432*8*2);
    u16* h0   = (u16*)alloc((size_t)256*1953*32*2);
    u16* h1   = (u16*)alloc((size_t)256*465*64*2);
    u16* h2   = (u16*)alloc((size_t)256*377*64*2);
    u16* h3   = (u16*)alloc((size_t)256*84*64*2);
    u16* h4   = (u16*)alloc((size_t)256*48*128*2);
    u16* h5   = (u16*)alloc((size_t)256*20*128*2);
    u16* fusedh = (u16*)alloc((size_t)256*256*2);
    float* gbuf = (float*)alloc((size_t)256*1536*4);

    // ---- one-time precompute ----
    MapP m0 = { map0, 64, 128, 64, 96*192 };
    MapP m1 = { map1, 31,  63, 32, 48*96 };
    k_map2<<<dim3(72, 2), 256, 0, stream>>>(m0, m1);
    WsP s0 = { sc0_w, wb0, 32,  6, 8, 25, 1, 200, 224, 32*1*224 };
    WsP s1 = { sc1_w, wb1, 64, 32, 32, 5, 5, 160, 160, 64*5*160 };
    k_wsph<<<dim3((64*5*160+255)/256, 2), 256, 0, stream>>>(s0, s1);
    WdP d2 = { c2_w, wb2,  64,  64, 3, 3, 9, 192, 64*3*192 };
    WdP d3 = { c3_w, wb3,  64,  64, 2, 2, 4, 128, 64*2*128 };
    WdP d4 = { c4_w, wb4, 128,  64, 3, 3, 9, 192, 128*3*192 };
    WdP d5 = { c5_w, wb5, 128, 128, 1, 9, 9, 128, 128*9*128 };
    k_wdir<<<dim3((128*9*128+255)/256, 4), 256, 0, stream>>>(d2, d3, d4, d5);
    HpP hp = { proj_w, gru_wih, gru_whh, pwh, wihh, whhh };
    k_hprep<<<dim3(2560, 3), 256, 0, stream>>>(hp);

    // ---- backbone (NHWC, MFMA f16) ----
    // k_nconv<CO,OW,NTOT,NB,IH,IW,KW,S,CI,TPC,NCH,KCm,KCp,NT_N,NT_CO>
    k_xu0<<<dim3(72, 256), 256, 0, stream>>>(x, map0, xu);
    k_nconv<32,63,1953,31, 96,192, 5,3, 8,25,1, 224,232, 4,2>
        <<<256*31, 256, 0, stream>>>(xu, wb0, bn0g,bn0b,bn0m,bn0v, h0);
    k_xu1<<<dim3(72, 256), 256, 0, stream>>>(h0, map1, xu);
    k_nconv<64,31,465,15, 48,96, 5,3, 32,5,5, 160,168, 2,4>
        <<<256*15, 256, 0, stream>>>(xu, wb1, bn1g,bn1b,bn1m,bn1v, h1);
    k_nconv<64,29,377,12, 15,31, 3,1, 64,3,3, 192,200, 2,4>
        <<<256*12, 256, 0, stream>>>(h1, wb2, bn2g,bn2b,bn2m,bn2v, h2);
    k_nconv<64,14,84,3, 13,29, 2,2, 64,2,2, 128,136, 2,4>
        <<<256*3,  256, 0, stream>>>(h2, wb3, bn3g,bn3b,bn3m,bn3v, h3);
    k_nconv<128,12,48,3, 6,14, 3,1, 64,3,3, 192,200, 1,8>
        <<<256*3,  256, 0, stream>>>(h3, wb4, bn4g,bn4b,bn4m,bn4v, h4);
    k_nconv<128,10,20,2, 4,12, 3,1, 128,1,9, 128,136, 1,8>
        <<<256*2,  256, 0, stream>>>(h4, wb5, bn5g,bn5b,bn5m,bn5v, h5);

    // ---- head (MFMA GEMMs) ----
    k_head2<<<dim3(4,4), 256, 0, stream>>>(h5, pwh, vin, vproj_w, vproj_b, fusedh);
    k_ggemm<<<dim3(4,24), 256, 0, stream>>>(fusedh, hx, wihh, whhh, gbuf);
    float* outp = (float*)d_out;
    k_gate<<<256, 256, 0, stream>>>(gbuf, hx, gru_bih, gru_bhh, outp + 1024);
    k_act<<<4, 256, 0, stream>>>(outp + 1024, fc_w, outp);
}

// Round 17
// 327.850 us; speedup vs baseline: 2.2289x; 1.0477x over previous
//
#include <hip/hip_runtime.h>
#include <math.h>

typedef unsigned short u16;
typedef unsigned int   u32;
typedef __attribute__((ext_vector_type(8))) _Float16 half8;
typedef __attribute__((ext_vector_type(4))) float    f32x4;

#define PI_F 3.14159265358979323846f

__device__ __forceinline__ float lrelu_f(float x){ return x >= 0.f ? x : 0.05f*x; }
__device__ __forceinline__ u16 f2h(float f){ _Float16 h = (_Float16)f; u16 u; __builtin_memcpy(&u,&h,2); return u; }
__device__ __forceinline__ float h2f(u16 u){ _Float16 h; __builtin_memcpy(&h,&u,2); return (float)h; }

// ---------------------------------------------------------------------------
// Index map in xu RASTER order (flat = oh*(Wo*9)+ow*9+kh*3+kw, the C-order
// reshape — R0-proven body; R9 lesson: never decode blockwise).
// ---------------------------------------------------------------------------
struct MapP { int* map; int H, W, Wo, total; };

__global__ void k_map2(MapP p0, MapP p1)
{
    MapP p = blockIdx.y ? p1 : p0;
    int i = blockIdx.x*blockDim.x + threadIdx.x;
    if (i >= p.total) return;
    int oh  = i / (p.Wo*9);
    int rem = i % (p.Wo*9);
    int ow  = rem / 9;
    int r2  = rem % 9;
    int kh  = r2/3, kw = r2%3;
    int ihc = min(oh*2, p.H-1);
    int lat = min(max(ihc + kh - 1, 0), p.H-1);
    float phi = ((float)lat + 0.5f)/(float)p.H * PI_F - 0.5f*PI_F;
    float ca  = fmaxf(fabsf(cosf(phi)), 1e-3f);
    float d   = fminf(0.8f/ca, 4.0f);
    float jw  = (float)((ow*2) % p.W);
    float lonf = rintf(jw + d*(float)(kw-1));   // np.round == rint (half-even)
    int lon = (int)lonf % p.W; if (lon < 0) lon += p.W;
    p.map[i] = lat*p.W + lon;
}

// ---------------------------------------------------------------------------
// xu0: NCHW fp32 x -> NHWC u16 [b][pos(96x192)][8] (ch 6,7 zero-padded).
// ---------------------------------------------------------------------------
__global__ void k_xu0(const float* __restrict__ x, const int* __restrict__ map,
                      u16* __restrict__ out)
{
    int p = blockIdx.x*blockDim.x + threadIdx.x;   // 0..18431
    int b = blockIdx.y;
    int m = map[p];
    const float* xb = x + (size_t)b*6*8192 + m;
    u16 v[8];
    #pragma unroll
    for (int c=0;c<6;++c) v[c] = f2h(xb[c*8192]);
    v[6]=0; v[7]=0;
    *reinterpret_cast<uint4*>(out + ((size_t)b*18432 + p)*8) =
        *reinterpret_cast<uint4*>(v);
}

// xu1: NHWC h0 [b][1953][32] -> NHWC xu1 [b][pos(48x96)][32], 16B vectorized.
__global__ void k_xu1(const u16* __restrict__ h0, const int* __restrict__ map,
                      u16* __restrict__ out)
{
    int i = blockIdx.x*blockDim.x + threadIdx.x;   // 0..18431 = pos*4+civ
    int b = blockIdx.y;
    int p = i >> 2, civ = i & 3;
    int m = map[p];
    uint4 v = *reinterpret_cast<const uint4*>(h0 + ((size_t)b*1953 + m)*32 + civ*8);
    *reinterpret_cast<uint4*>(out + ((size_t)b*4608 + p)*32 + civ*8) = v;
}

// ---------------------------------------------------------------------------
// Weights, NHWC-k chunked layout [co][ch][KCm], k-within-chunk = tl*CIP + ci
// (channel-fastest). Pad cols/channels/taps zero -> inert in MFMA.
// Sphere: fold avg_pool3(conv3x3) -> 5x5/stride3 (R4-verified).
// R16: tap >= 25 guard (L0 now K-chunked: NCH=2 x TPC=13 = 26 tap slots).
// ---------------------------------------------------------------------------
struct WsP { const float* w3; u16* wh; int CO, CI, CIP, TPC, NCH, KCd, KCm, total; };

__global__ void k_wsph(WsP p0, WsP p1)
{
    WsP p = blockIdx.y ? p1 : p0;
    int i = blockIdx.x*blockDim.x + threadIdx.x;
    if (i >= p.total) return;
    int j = i % p.KCm, t = i / p.KCm;
    int ch = t % p.NCH, co = t / p.NCH;
    float s = 0.f;
    if (j < p.KCd){
        int tl = j / p.CIP, ci = j % p.CIP;
        int tap = ch*p.TPC + tl;
        if (ci < p.CI && tap < 25){
            int u = tap/5, v = tap%5;
            const float* w = p.w3 + (co*p.CI + ci)*9;
            int pl0 = max(0, u-2), pl1 = min(2, u);
            int q0 = max(0, v-2), q1 = min(2, v);
            for (int pl=pl0; pl<=pl1; ++pl)
                for (int q=q0; q<=q1; ++q) s += w[pl*3+q];
            s *= (1.0f/9.0f);
        }
    }
    p.wh[i] = f2h(s);
}

struct WdP { const float* w; u16* wh; int CO, CI, TPC, NCH, KPQ, KCm, total; };

__global__ void k_wdir(WdP p0, WdP p1, WdP p2, WdP p3)
{
    WdP p = (blockIdx.y==0)?p0 : (blockIdx.y==1)?p1 : (blockIdx.y==2)?p2 : p3;
    int i = blockIdx.x*blockDim.x + threadIdx.x;
    if (i >= p.total) return;
    int j = i % p.KCm, t = i / p.KCm;
    int ch = t % p.NCH, co = t / p.NCH;
    int tl = j / p.CI, ci = j % p.CI;
    int tap = ch*p.TPC + tl;
    p.wh[i] = f2h(p.w[(size_t)(co*p.CI + ci)*p.KPQ + tap]);
}

// ---------------------------------------------------------------------------
// Head/GRU weight prep (R15-verified). pwh columns permuted to NHWC-flat
// order: k_nhwc = pos*128+co  <->  k_ref = co*20+pos.
// ---------------------------------------------------------------------------
struct HpP { const float* pw; const float* wih; const float* whh;
             u16* pwh; u16* wihh; u16* whhh; };

__global__ void k_hprep(HpP p)
{
    int i = blockIdx.x*blockDim.x + threadIdx.x;
    int y = blockIdx.y;
    if (y == 0){
        if (i >= 256*2560) return;
        int n = i / 2560, k = i % 2560;
        int pos = k >> 7, co = k & 127;
        p.pwh[i] = f2h(p.pw[(size_t)n*2560 + co*20 + pos]);
    } else if (y == 1){
        if (i >= 768*256) return;
        p.wihh[i] = f2h(p.wih[i]);
    } else {
        if (i >= 768*256) return;
        p.whhh[i] = f2h(p.whh[i]);
    }
}

// ---------------------------------------------------------------------------
// NHWC MFMA conv engine with 2-D WAVE TILING (R16 post-mortem: L1 was
// LDS-read-throughput bound at 1.5 fragment-reads/MFMA; wave (wr,wc) now
// owns WN x WM 16x16 tiles -> (WN+WM) reads per WN*WM MFMAs = 1.0 at 2x2).
// Fragment layout (guide §3, m89-verified): A/B lane&15 = M/N, k=(lane>>4)*8+j;
// D col=lane&15 (-> co), row=(lane>>4)*4+reg (-> n).
// ---------------------------------------------------------------------------
template<int CO,int OW,int NTOT,int NB,int IH,int IW,int KW,int S,int CI,
         int TPC,int NCH,int KCm,int KCp,int WR,int WC,int WN,int WM>
__global__ __launch_bounds__(256) void k_nconv(
    const u16* __restrict__ in, const u16* __restrict__ wh,
    const float* __restrict__ bg, const float* __restrict__ bb,
    const float* __restrict__ bm, const float* __restrict__ bv,
    u16* __restrict__ out)
{
    constexpr int NT_N = WR*WN;
    constexpr int NPAD = NT_N*16;
    constexpr int KCd  = TPC*CI;
    constexpr int CIV  = CI/8;
    static_assert(WR*WC == 4, "4 waves");
    static_assert(WC*WM*16 == CO, "co tiling covers CO");
    static_assert(CI % 8 == 0, "16B staging vectors");
    static_assert(KCm % 32 == 0 && KCp % 8 == 0 && KCd <= KCm, "tiling");
    static_assert((NPAD & (NPAD-1)) == 0, "NPAD pow2");
    __shared__ __align__(16) u16 sA[NPAD*KCp];
    __shared__ __align__(16) u16 sB[CO*KCp];

    int b  = blockIdx.x / NB;
    int n0 = (blockIdx.x % NB)*NPAD;
    int tid = threadIdx.x;
    const u16* xb = in + (size_t)b*IH*IW*CI;

    if constexpr (KCm > KCd){
        constexpr int PADW = KCm - KCd;
        for (int e = tid; e < NPAD*PADW; e += 256)
            sA[(e/PADW)*KCp + KCd + e%PADW] = 0;
    }

    int w = tid >> 6, lane = tid & 63, l15 = lane & 15, l4 = lane >> 4;
    int wr = w / WC, wc = w % WC;
    f32x4 acc[WN][WM];
    #pragma unroll
    for (int i=0;i<WN;++i)
        #pragma unroll
        for (int j=0;j<WM;++j) acc[i][j] = (f32x4){0.f,0.f,0.f,0.f};

    for (int ch = 0; ch < NCH; ++ch){
        if (ch) __syncthreads();
        // stage A: per (n, tap, ch-vec8) one 16B copy; tap row is contiguous
        constexpr int ITER = NPAD*TPC*CIV;
        for (int i = tid; i < ITER; i += 256){
            int n_l = i / (TPC*CIV);
            int r   = i - n_l*(TPC*CIV);
            int tl  = r / CIV;
            int civ = r - tl*CIV;
            int n_g = min(n0 + n_l, NTOT-1);
            int oh = n_g/OW, ow = n_g - oh*OW;
            int tap = ch*TPC + tl;
            int u = tap/KW, v = tap - u*KW;
            int pos = (oh*S + u)*IW + ow*S + v;
            uint4 val = *reinterpret_cast<const uint4*>(xb + (size_t)pos*CI + civ*8);
            *reinterpret_cast<uint4*>(&sA[n_l*KCp + tl*CI + civ*8]) = val;
        }
        // stage B: weights (16B copies)
        constexpr int W8 = KCm/8;
        for (int i = tid; i < CO*W8; i += 256){
            int co = i / W8, j = (i - co*W8)*8;
            uint4 v = *reinterpret_cast<const uint4*>(wh + ((size_t)co*NCH + ch)*KCm + j);
            *reinterpret_cast<uint4*>(&sB[co*KCp + j]) = v;
        }
        __syncthreads();
        // MFMA: wave (wr,wc) computes WN x WM tiles; (WN+WM) reads per step
        #pragma unroll
        for (int ks = 0; ks < KCm/32; ++ks){
            half8 a[WN], bf[WM];
            #pragma unroll
            for (int i=0;i<WN;++i)
                a[i] = *reinterpret_cast<const half8*>(
                    &sA[((wr*WN+i)*16 + l15)*KCp + ks*32 + l4*8]);
            #pragma unroll
            for (int j=0;j<WM;++j)
                bf[j] = *reinterpret_cast<const half8*>(
                    &sB[((wc*WM+j)*16 + l15)*KCp + ks*32 + l4*8]);
            #pragma unroll
            for (int i=0;i<WN;++i)
                #pragma unroll
                for (int j=0;j<WM;++j)
                    acc[i][j] = __builtin_amdgcn_mfma_f32_16x16x32_f16(a[i], bf[j], acc[i][j], 0, 0, 0);
        }
    }
    // epilogue: BN + lrelu, NHWC [b][n][co] (lanes -> consecutive co: coalesced)
    #pragma unroll
    for (int j=0;j<WM;++j){
        int co = (wc*WM+j)*16 + l15;
        float inv = bg[co]*rsqrtf(bv[co]+1e-5f);
        float shv = bb[co] - bm[co]*inv;
        #pragma unroll
        for (int i=0;i<WN;++i){
            #pragma unroll
            for (int r=0;r<4;++r){
                int gn = n0 + (wr*WN+i)*16 + l4*4 + r;
                if (gn < NTOT)
                    out[((size_t)b*NTOT + gn)*CO + co] = f2h(lrelu_f(fmaf(acc[i][j][r], inv, shv)));
            }
        }
    }
}

// ---------------------------------------------------------------------------
// Head GEMM: fused = lrelu(h5flat[256x2560] @ pwh^T + v@vproj^T + vproj_b).
// 64x64 tiles, grid(4,4). Output f16. (R15-verified.)
// ---------------------------------------------------------------------------
__global__ __launch_bounds__(256) void k_head2(
    const u16* __restrict__ h5, const u16* __restrict__ pwh,
    const float* __restrict__ vin, const float* __restrict__ vproj_w,
    const float* __restrict__ vproj_b, u16* __restrict__ fusedh)
{
    __shared__ __align__(16) u16 sA[64*136];
    __shared__ __align__(16) u16 sB[64*136];
    __shared__ float sv[64*9];
    int m0 = blockIdx.x*64, nc0 = blockIdx.y*64;
    int tid = threadIdx.x;
    int w = tid >> 6, lane = tid & 63, l15 = lane & 15, l4 = lane >> 4;
    f32x4 acc[4];
    #pragma unroll
    for (int j=0;j<4;++j) acc[j] = (f32x4){0.f,0.f,0.f,0.f};

    for (int i = tid; i < 576; i += 256) sv[i] = vin[(m0 + i/9)*9 + i%9];

    for (int kc0 = 0; kc0 < 2560; kc0 += 128){
        if (kc0) __syncthreads();
        for (int i = tid; i < 1024; i += 256){
            int r = i >> 4, jv = (i & 15)*8;
            *reinterpret_cast<uint4*>(&sA[r*136 + jv]) =
                *reinterpret_cast<const uint4*>(h5 + (size_t)(m0+r)*2560 + kc0 + jv);
            *reinterpret_cast<uint4*>(&sB[r*136 + jv]) =
                *reinterpret_cast<const uint4*>(pwh + (size_t)(nc0+r)*2560 + kc0 + jv);
        }
        __syncthreads();
        #pragma unroll
        for (int ks = 0; ks < 4; ++ks){
            half8 a = *reinterpret_cast<const half8*>(&sA[(w*16 + l15)*136 + ks*32 + l4*8]);
            #pragma unroll
            for (int j=0;j<4;++j){
                half8 bf = *reinterpret_cast<const half8*>(&sB[(j*16 + l15)*136 + ks*32 + l4*8]);
                acc[j] = __builtin_amdgcn_mfma_f32_16x16x32_f16(a, bf, acc[j], 0, 0, 0);
            }
        }
    }
    #pragma unroll
    for (int j=0;j<4;++j){
        int nc = nc0 + j*16 + l15;
        float bias = vproj_b[nc];
        #pragma unroll
        for (int r=0;r<4;++r){
            int ml = w*16 + l4*4 + r;
            float av = 0.f;
            #pragma unroll
            for (int k=0;k<9;++k) av = fmaf(sv[ml*9+k], vproj_w[nc*9+k], av);
            fusedh[(size_t)(m0+ml)*256 + nc] = f2h(lrelu_f(acc[j][r] + av + bias));
        }
    }
}

// ---------------------------------------------------------------------------
// GRU gate GEMM: gbuf[:,0:768] = fused @ wih^T ; gbuf[:,768:1536] = hx @ whh^T.
// grid(4, 24): y = half*12 + ntile. (R15-verified.)
// ---------------------------------------------------------------------------
__global__ __launch_bounds__(256) void k_ggemm(
    const u16* __restrict__ fusedh, const float* __restrict__ hx,
    const u16* __restrict__ wihh, const u16* __restrict__ whhh,
    float* __restrict__ gbuf)
{
    __shared__ __align__(16) u16 sA[64*136];
    __shared__ __align__(16) u16 sB[64*136];
    int m0 = blockIdx.x*64;
    int t  = blockIdx.y;
    int half = t / 12, nt = t - half*12;
    int n0 = nt*64;
    const u16* B = (half ? whhh : wihh) + (size_t)n0*256;
    int tid = threadIdx.x;
    int w = tid >> 6, lane = tid & 63, l15 = lane & 15, l4 = lane >> 4;
    f32x4 acc[4];
    #pragma unroll
    for (int j=0;j<4;++j) acc[j] = (f32x4){0.f,0.f,0.f,0.f};

    for (int kc0 = 0; kc0 < 256; kc0 += 128){
        if (kc0) __syncthreads();
        for (int i = tid; i < 1024; i += 256){
            int r = i >> 4, jv = (i & 15)*8;
            if (half == 0){
                *reinterpret_cast<uint4*>(&sA[r*136 + jv]) =
                    *reinterpret_cast<const uint4*>(fusedh + (size_t)(m0+r)*256 + kc0 + jv);
            } else {
                const float* src = hx + (size_t)(m0+r)*256 + kc0 + jv;
                float4 f0 = *reinterpret_cast<const float4*>(src);
                float4 f1 = *reinterpret_cast<const float4*>(src+4);
                u16 v[8] = { f2h(f0.x),f2h(f0.y),f2h(f0.z),f2h(f0.w),
                             f2h(f1.x),f2h(f1.y),f2h(f1.z),f2h(f1.w) };
                *reinterpret_cast<uint4*>(&sA[r*136 + jv]) = *reinterpret_cast<uint4*>(v);
            }
            *reinterpret_cast<uint4*>(&sB[r*136 + jv]) =
                *reinterpret_cast<const uint4*>(B + (size_t)r*256 + kc0 + jv);
        }
        __syncthreads();
        #pragma unroll
        for (int ks = 0; ks < 4; ++ks){
            half8 a = *reinterpret_cast<const half8*>(&sA[(w*16 + l15)*136 + ks*32 + l4*8]);
            #pragma unroll
            for (int j=0;j<4;++j){
                half8 bf = *reinterpret_cast<const half8*>(&sB[(j*16 + l15)*136 + ks*32 + l4*8]);
                acc[j] = __builtin_amdgcn_mfma_f32_16x16x32_f16(a, bf, acc[j], 0, 0, 0);
            }
        }
    }
    #pragma unroll
    for (int j=0;j<4;++j){
        int nc = half*768 + n0 + j*16 + l15;
        #pragma unroll
        for (int r=0;r<4;++r){
            int m = m0 + w*16 + l4*4 + r;
            gbuf[(size_t)m*1536 + nc] = acc[j][r];
        }
    }
}

// pointwise GRU update
__global__ __launch_bounds__(256) void k_gate(
    const float* __restrict__ gbuf, const float* __restrict__ hx,
    const float* __restrict__ bih, const float* __restrict__ bhh,
    float* __restrict__ hx_new)
{
    int b = blockIdx.x, j = threadIdx.x;
    const float* g = gbuf + (size_t)b*1536;
    float ir = g[j]       + bih[j];
    float iz = g[256+j]   + bih[256+j];
    float in_= g[512+j]   + bih[512+j];
    float hr = g[768+j]   + bhh[j];
    float hz = g[1024+j]  + bhh[256+j];
    float hn = g[1280+j]  + bhh[512+j];
    float r = 1.f/(1.f+expf(-(ir+hr)));
    float z = 1.f/(1.f+expf(-(iz+hz)));
    float n = tanhf(in_ + r*hn);
    hx_new[b*256+j] = (1.f-z)*n + z*hx[b*256+j];
}

// act = lrelu(hx_new) @ fc_w.T
__global__ void k_act(const float* __restrict__ hx_new, const float* __restrict__ fc_w,
                      float* __restrict__ act)
{
    int t = blockIdx.x*blockDim.x + threadIdx.x;
    if (t >= 1024) return;
    int b = t >> 2, o = t & 3;
    const float* h = hx_new + b*256;
    const float* w = fc_w + o*256;
    float acc = 0.f;
    for (int k=0;k<256;++k) acc = fmaf(lrelu_f(h[k]), w[k], acc);
    act[t] = acc;
}

extern "C" void kernel_launch(void* const* d_in, const int* in_sizes, int n_in,
                              void* d_out, int out_size, void* d_ws, size_t ws_size,
                              hipStream_t stream)
{
    const float* x      = (const float*)d_in[0];
    const float* vin    = (const float*)d_in[1];
    const float* hx     = (const float*)d_in[2];
    const float* sc0_w  = (const float*)d_in[3];
    const float* bn0g   = (const float*)d_in[4];
    const float* bn0b   = (const float*)d_in[5];
    const float* bn0m   = (const float*)d_in[6];
    const float* bn0v   = (const float*)d_in[7];
    const float* sc1_w  = (const float*)d_in[8];
    const float* bn1g   = (const float*)d_in[9];
    const float* bn1b   = (const float*)d_in[10];
    const float* bn1m   = (const float*)d_in[11];
    const float* bn1v   = (const float*)d_in[12];
    const float* c2_w   = (const float*)d_in[13];
    const float* bn2g   = (const float*)d_in[14];
    const float* bn2b   = (const float*)d_in[15];
    const float* bn2m   = (const float*)d_in[16];
    const float* bn2v   = (const float*)d_in[17];
    const float* c3_w   = (const float*)d_in[18];
    const float* bn3g   = (const float*)d_in[19];
    const float* bn3b   = (const float*)d_in[20];
    const float* bn3m   = (const float*)d_in[21];
    const float* bn3v   = (const float*)d_in[22];
    const float* c4_w   = (const float*)d_in[23];
    const float* bn4g   = (const float*)d_in[24];
    const float* bn4b   = (const float*)d_in[25];
    const float* bn4m   = (const float*)d_in[26];
    const float* bn4v   = (const float*)d_in[27];
    const float* c5_w   = (const float*)d_in[28];
    const float* bn5g   = (const float*)d_in[29];
    const float* bn5b   = (const float*)d_in[30];
    const float* bn5m   = (const float*)d_in[31];
    const float* bn5v   = (const float*)d_in[32];
    const float* proj_w = (const float*)d_in[33];
    const float* vproj_w= (const float*)d_in[34];
    const float* vproj_b= (const float*)d_in[35];
    const float* gru_wih= (const float*)d_in[36];
    const float* gru_whh= (const float*)d_in[37];
    const float* gru_bih= (const float*)d_in[38];
    const float* gru_bhh= (const float*)d_in[39];
    const float* fc_w   = (const float*)d_in[40];

    char* base = (char*)d_ws;
    size_t off = 0;
    auto alloc = [&](size_t bytes)->char*{
        char* p = base + off; off += (bytes + 255) & ~(size_t)255; return p;
    };
    int* map0 = (int*)alloc((size_t)96*192*4);
    int* map1 = (int*)alloc((size_t)48*96*4);
    u16* wb0  = (u16*)alloc((size_t)32*2*128*2);
    u16* wb1  = (u16*)alloc((size_t)64*5*160*2);
    u16* wb2  = (u16*)alloc((size_t)64*3*192*2);
    u16* wb3  = (u16*)alloc((size_t)64*2*128*2);
    u16* wb4  = (u16*)alloc((size_t)128*3*192*2);
    u16* wb5  = (u16*)alloc((size_t)128*9*128*2);
    u16* pwh  = (u16*)alloc((size_t)256*2560*2);
    u16* wihh = (u16*)alloc((size_t)768*256*2);
    u16* whhh = (u16*)alloc((size_t)768*256*2);
    // xu0 [256][18432][8] and xu1 [256][4608][32] are both 75.5MB, disjoint
    // lifetimes -> share one region
    u16* xu   = (u16*)alloc((size_t)256*18432*8*2);
    u16* h0   = (u16*)alloc((size_t)256*1953*32*2);
    u16* h1   = (u16*)alloc((size_t)256*465*64*2);
    u16* h2   = (u16*)alloc((size_t)256*377*64*2);
    u16* h3   = (u16*)alloc((size_t)256*84*64*2);
    u16* h4   = (u16*)alloc((size_t)256*48*128*2);
    u16* h5   = (u16*)alloc((size_t)256*20*128*2);
    u16* fusedh = (u16*)alloc((size_t)256*256*2);
    float* gbuf = (float*)alloc((size_t)256*1536*4);

    // ---- one-time precompute ----
    MapP m0 = { map0, 64, 128, 64, 96*192 };
    MapP m1 = { map1, 31,  63, 32, 48*96 };
    k_map2<<<dim3(72, 2), 256, 0, stream>>>(m0, m1);
    WsP s0 = { sc0_w, wb0, 32,  6, 8, 13, 2, 104, 128, 32*2*128 };
    WsP s1 = { sc1_w, wb1, 64, 32, 32, 5, 5, 160, 160, 64*5*160 };
    k_wsph<<<dim3((64*5*160+255)/256, 2), 256, 0, stream>>>(s0, s1);
    WdP d2 = { c2_w, wb2,  64,  64, 3, 3, 9, 192, 64*3*192 };
    WdP d3 = { c3_w, wb3,  64,  64, 2, 2, 4, 128, 64*2*128 };
    WdP d4 = { c4_w, wb4, 128,  64, 3, 3, 9, 192, 128*3*192 };
    WdP d5 = { c5_w, wb5, 128, 128, 1, 9, 9, 128, 128*9*128 };
    k_wdir<<<dim3((128*9*128+255)/256, 4), 256, 0, stream>>>(d2, d3, d4, d5);
    HpP hp = { proj_w, gru_wih, gru_whh, pwh, wihh, whhh };
    k_hprep<<<dim3(2560, 3), 256, 0, stream>>>(hp);

    // ---- backbone (NHWC, MFMA f16, 2-D wave tiles) ----
    // k_nconv<CO,OW,NTOT,NB,IH,IW,KW,S,CI,TPC,NCH,KCm,KCp,WR,WC,WN,WM>
    k_xu0<<<dim3(72, 256), 256, 0, stream>>>(x, map0, xu);
    k_nconv<32,63,1953,16, 96,192, 5,3, 8,13,2, 128,136, 4,1,2,2>
        <<<256*16, 256, 0, stream>>>(xu, wb0, bn0g,bn0b,bn0m,bn0v, h0);
    k_xu1<<<dim3(72, 256), 256, 0, stream>>>(h0, map1, xu);
    k_nconv<64,31,465,8, 48,96, 5,3, 32,5,5, 160,168, 2,2,2,2>
        <<<256*8, 256, 0, stream>>>(xu, wb1, bn1g,bn1b,bn1m,bn1v, h1);
    k_nconv<64,29,377,6, 15,31, 3,1, 64,3,3, 192,200, 2,2,2,2>
        <<<256*6, 256, 0, stream>>>(h1, wb2, bn2g,bn2b,bn2m,bn2v, h2);
    k_nconv<64,14,84,3, 13,29, 2,2, 64,2,2, 128,136, 2,2,1,2>
        <<<256*3, 256, 0, stream>>>(h2, wb3, bn3g,bn3b,bn3m,bn3v, h3);
    k_nconv<128,12,48,3, 6,14, 3,1, 64,3,3, 192,200, 1,4,1,2>
        <<<256*3, 256, 0, stream>>>(h3, wb4, bn4g,bn4b,bn4m,bn4v, h4);
    k_nconv<128,10,20,2, 4,12, 3,1, 128,1,9, 128,136, 1,4,1,2>
        <<<256*2, 256, 0, stream>>>(h4, wb5, bn5g,bn5b,bn5m,bn5v, h5);

    // ---- head (MFMA GEMMs) ----
    k_head2<<<dim3(4,4), 256, 0, stream>>>(h5, pwh, vin, vproj_w, vproj_b, fusedh);
    k_ggemm<<<dim3(4,24), 256, 0, stream>>>(fusedh, hx, wihh, whhh, gbuf);
    float* outp = (float*)d_out;
    k_gate<<<256, 256, 0, stream>>>(gbuf, hx, gru_bih, gru_bhh, outp + 1024);
    k_act<<<4, 256, 0, stream>>>(outp + 1024, fc_w, outp);
}

// Round 18
// 306.271 us; speedup vs baseline: 2.3859x; 1.0705x over previous
//
#include <hip/hip_runtime.h>
#include <math.h>

typedef unsigned short u16;
typedef unsigned int   u32;
typedef __attribute__((ext_vector_type(8))) _Float16 half8;
typedef __attribute__((ext_vector_type(4))) float    f32x4;

#define PI_F 3.14159265358979323846f

__device__ __forceinline__ float lrelu_f(float x){ return x >= 0.f ? x : 0.05f*x; }
__device__ __forceinline__ u16 f2h(float f){ _Float16 h = (_Float16)f; u16 u; __builtin_memcpy(&u,&h,2); return u; }
__device__ __forceinline__ float h2f(u16 u){ _Float16 h; __builtin_memcpy(&h,&u,2); return (float)h; }

// ---------------------------------------------------------------------------
// Consolidated one-time prep (R17: 4 prep kernels -> 1 launch; bodies are the
// R15/R16-verified ones, dispatched by blockIdx.y).
//  map: xu RASTER order (flat = oh*(Wo*9)+ow*9+kh*3+kw, C-order reshape — R9
//  lesson: never decode blockwise).  Weights: NHWC-k chunked [co][ch][KCm],
//  k-within-chunk = tl*CIP+ci; pad cols/channels/taps zero -> inert in MFMA.
//  pwh columns permuted to NHWC-flat: k_nhwc = pos*128+co <-> k_ref = co*20+pos.
// ---------------------------------------------------------------------------
struct PrepP {
    int *map0, *map1;
    const float *sc0_w, *sc1_w;
    u16 *wb0, *wb1;
    const float *c2_w, *c3_w, *c4_w, *c5_w;
    u16 *wb2, *wb3, *wb4, *wb5;
    const float *pw, *wih, *whh;
    u16 *pwh, *wihh, *whhh;
};

__device__ void d_map(int* map, int H, int W, int Wo, int total, int i)
{
    if (i >= total) return;
    int oh  = i / (Wo*9);
    int rem = i % (Wo*9);
    int ow  = rem / 9;
    int r2  = rem % 9;
    int kh  = r2/3, kw = r2%3;
    int ihc = min(oh*2, H-1);
    int lat = min(max(ihc + kh - 1, 0), H-1);
    float phi = ((float)lat + 0.5f)/(float)H * PI_F - 0.5f*PI_F;
    float ca  = fmaxf(fabsf(cosf(phi)), 1e-3f);
    float d   = fminf(0.8f/ca, 4.0f);
    float jw  = (float)((ow*2) % W);
    float lonf = rintf(jw + d*(float)(kw-1));   // np.round == rint (half-even)
    int lon = (int)lonf % W; if (lon < 0) lon += W;
    map[i] = lat*W + lon;
}

__device__ void d_wsph(const float* w3, u16* wh, int CO, int CI, int CIP,
                       int TPC, int NCH, int KCd, int KCm, int total, int i)
{
    if (i >= total) return;
    int j = i % KCm, t = i / KCm;
    int ch = t % NCH, co = t / NCH;
    float s = 0.f;
    if (j < KCd){
        int tl = j / CIP, ci = j % CIP;
        int tap = ch*TPC + tl;
        if (ci < CI && tap < 25){
            int u = tap/5, v = tap%5;
            const float* w = w3 + (co*CI + ci)*9;
            int pl0 = max(0, u-2), pl1 = min(2, u);
            int q0 = max(0, v-2), q1 = min(2, v);
            for (int pl=pl0; pl<=pl1; ++pl)
                for (int q=q0; q<=q1; ++q) s += w[pl*3+q];
            s *= (1.0f/9.0f);
        }
    }
    wh[i] = f2h(s);
}

__device__ void d_wdir(const float* w, u16* wh, int CO, int CI, int TPC,
                       int NCH, int KPQ, int KCm, int total, int i)
{
    if (i >= total) return;
    int j = i % KCm, t = i / KCm;
    int ch = t % NCH, co = t / NCH;
    int tl = j / CI, ci = j % CI;
    int tap = ch*TPC + tl;
    wh[i] = f2h(w[(size_t)(co*CI + ci)*KPQ + tap]);
}

__global__ void k_prep(PrepP p)
{
    int i = blockIdx.x*blockDim.x + threadIdx.x;
    switch (blockIdx.y){
    case 0:  d_map(p.map0, 64, 128, 64, 18432, i); break;
    case 1:  d_map(p.map1, 31,  63, 32,  4608, i); break;
    case 2:  d_wsph(p.sc0_w, p.wb0, 32,  6,  8, 13, 2, 104, 128,  8192, i); break;
    case 3:  d_wsph(p.sc1_w, p.wb1, 64, 32, 32,  5, 5, 160, 160, 51200, i); break;
    case 4:  d_wdir(p.c2_w, p.wb2,  64,  64, 3, 3, 9, 192,  36864, i); break;
    case 5:  d_wdir(p.c3_w, p.wb3,  64,  64, 2, 2, 4, 128,  16384, i); break;
    case 6:  d_wdir(p.c4_w, p.wb4, 128,  64, 3, 3, 9, 192,  73728, i); break;
    case 7:  d_wdir(p.c5_w, p.wb5, 128, 128, 1, 9, 9, 128, 147456, i); break;
    case 8:  if (i < 256*2560){
                 int n = i / 2560, k = i % 2560;
                 int pos = k >> 7, co = k & 127;
                 p.pwh[i] = f2h(p.pw[(size_t)n*2560 + co*20 + pos]);
             } break;
    case 9:  if (i < 768*256) p.wihh[i] = f2h(p.wih[i]); break;
    default: if (i < 768*256) p.whhh[i] = f2h(p.whh[i]); break;
    }
}

// ---------------------------------------------------------------------------
// xu0: NCHW fp32 x -> NHWC u16 [b][pos(96x192)][8] (ch 6,7 zero-padded).
// (xu1 is no longer materialized — folded into L1's stage A, R17.)
// ---------------------------------------------------------------------------
__global__ void k_xu0(const float* __restrict__ x, const int* __restrict__ map,
                      u16* __restrict__ out)
{
    int p = blockIdx.x*blockDim.x + threadIdx.x;   // 0..18431
    int b = blockIdx.y;
    int m = map[p];
    const float* xb = x + (size_t)b*6*8192 + m;
    u16 v[8];
    #pragma unroll
    for (int c=0;c<6;++c) v[c] = f2h(xb[c*8192]);
    v[6]=0; v[7]=0;
    *reinterpret_cast<uint4*>(out + ((size_t)b*18432 + p)*8) =
        *reinterpret_cast<uint4*>(v);
}

// ---------------------------------------------------------------------------
// NHWC MFMA conv engine, 2-D wave tiling (R16/R17-verified). R17 adds a
// GATHER path: stage A indirects through the xu raster map (L1-resident,
// 18 KB) instead of reading a materialized xu buffer — saves the xu1
// kernel's 75 MB write + re-read; values are bit-identical.
// Fragment layout (guide §3, m89-verified): A/B lane&15 = M/N, k=(lane>>4)*8+j;
// D col=lane&15 (-> co), row=(lane>>4)*4+reg (-> n).
// ---------------------------------------------------------------------------
template<int CO,int OW,int NTOT,int NB,int IH,int IW,int KW,int S,int CI,
         int TPC,int NCH,int KCm,int KCp,int WR,int WC,int WN,int WM,
         int GATHER=0,int INTOT=0>
__global__ __launch_bounds__(256) void k_nconv(
    const u16* __restrict__ in, const int* __restrict__ map,
    const u16* __restrict__ wh,
    const float* __restrict__ bg, const float* __restrict__ bb,
    const float* __restrict__ bm, const float* __restrict__ bv,
    u16* __restrict__ out)
{
    constexpr int NT_N = WR*WN;
    constexpr int NPAD = NT_N*16;
    constexpr int KCd  = TPC*CI;
    constexpr int CIV  = CI/8;
    static_assert(WR*WC == 4, "4 waves");
    static_assert(WC*WM*16 == CO, "co tiling covers CO");
    static_assert(CI % 8 == 0, "16B staging vectors");
    static_assert(KCm % 32 == 0 && KCp % 8 == 0 && KCd <= KCm, "tiling");
    static_assert((NPAD & (NPAD-1)) == 0, "NPAD pow2");
    __shared__ __align__(16) u16 sA[NPAD*KCp];
    __shared__ __align__(16) u16 sB[CO*KCp];

    int b  = blockIdx.x / NB;
    int n0 = (blockIdx.x % NB)*NPAD;
    int tid = threadIdx.x;
    const u16* xb = in + (GATHER ? (size_t)b*INTOT*CI : (size_t)b*IH*IW*CI);

    if constexpr (KCm > KCd){
        constexpr int PADW = KCm - KCd;
        for (int e = tid; e < NPAD*PADW; e += 256)
            sA[(e/PADW)*KCp + KCd + e%PADW] = 0;
    }

    int w = tid >> 6, lane = tid & 63, l15 = lane & 15, l4 = lane >> 4;
    int wr = w / WC, wc = w % WC;
    f32x4 acc[WN][WM];
    #pragma unroll
    for (int i=0;i<WN;++i)
        #pragma unroll
        for (int j=0;j<WM;++j) acc[i][j] = (f32x4){0.f,0.f,0.f,0.f};

    for (int ch = 0; ch < NCH; ++ch){
        if (ch) __syncthreads();
        // stage A: per (n, tap, ch-vec8) one 16B copy; tap row is contiguous
        constexpr int ITER = NPAD*TPC*CIV;
        for (int i = tid; i < ITER; i += 256){
            int n_l = i / (TPC*CIV);
            int r   = i - n_l*(TPC*CIV);
            int tl  = r / CIV;
            int civ = r - tl*CIV;
            int n_g = min(n0 + n_l, NTOT-1);
            int oh = n_g/OW, ow = n_g - oh*OW;
            int tap = ch*TPC + tl;
            int u = tap/KW, v = tap - u*KW;
            int pos = (oh*S + u)*IW + ow*S + v;
            const u16* src;
            if constexpr (GATHER){
                int m = map[pos];                    // L1-hot raster map
                src = xb + (size_t)m*CI + civ*8;
            } else {
                src = xb + (size_t)pos*CI + civ*8;
            }
            uint4 val = *reinterpret_cast<const uint4*>(src);
            *reinterpret_cast<uint4*>(&sA[n_l*KCp + tl*CI + civ*8]) = val;
        }
        // stage B: weights (16B copies)
        constexpr int W8 = KCm/8;
        for (int i = tid; i < CO*W8; i += 256){
            int co = i / W8, j = (i - co*W8)*8;
            uint4 v = *reinterpret_cast<const uint4*>(wh + ((size_t)co*NCH + ch)*KCm + j);
            *reinterpret_cast<uint4*>(&sB[co*KCp + j]) = v;
        }
        __syncthreads();
        // MFMA: wave (wr,wc) computes WN x WM tiles; (WN+WM) reads per step
        #pragma unroll
        for (int ks = 0; ks < KCm/32; ++ks){
            half8 a[WN], bf[WM];
            #pragma unroll
            for (int i=0;i<WN;++i)
                a[i] = *reinterpret_cast<const half8*>(
                    &sA[((wr*WN+i)*16 + l15)*KCp + ks*32 + l4*8]);
            #pragma unroll
            for (int j=0;j<WM;++j)
                bf[j] = *reinterpret_cast<const half8*>(
                    &sB[((wc*WM+j)*16 + l15)*KCp + ks*32 + l4*8]);
            #pragma unroll
            for (int i=0;i<WN;++i)
                #pragma unroll
                for (int j=0;j<WM;++j)
                    acc[i][j] = __builtin_amdgcn_mfma_f32_16x16x32_f16(a[i], bf[j], acc[i][j], 0, 0, 0);
        }
    }
    // epilogue: BN + lrelu, NHWC [b][n][co] (lanes -> consecutive co: coalesced)
    #pragma unroll
    for (int j=0;j<WM;++j){
        int co = (wc*WM+j)*16 + l15;
        float inv = bg[co]*rsqrtf(bv[co]+1e-5f);
        float shv = bb[co] - bm[co]*inv;
        #pragma unroll
        for (int i=0;i<WN;++i){
            #pragma unroll
            for (int r=0;r<4;++r){
                int gn = n0 + (wr*WN+i)*16 + l4*4 + r;
                if (gn < NTOT)
                    out[((size_t)b*NTOT + gn)*CO + co] = f2h(lrelu_f(fmaf(acc[i][j][r], inv, shv)));
            }
        }
    }
}

// ---------------------------------------------------------------------------
// Head GEMM: fused = lrelu(h5flat[256x2560] @ pwh^T + v@vproj^T + vproj_b).
// 64x64 tiles, grid(4,4). Output f16. (R15-verified.)
// ---------------------------------------------------------------------------
__global__ __launch_bounds__(256) void k_head2(
    const u16* __restrict__ h5, const u16* __restrict__ pwh,
    const float* __restrict__ vin, const float* __restrict__ vproj_w,
    const float* __restrict__ vproj_b, u16* __restrict__ fusedh)
{
    __shared__ __align__(16) u16 sA[64*136];
    __shared__ __align__(16) u16 sB[64*136];
    __shared__ float sv[64*9];
    int m0 = blockIdx.x*64, nc0 = blockIdx.y*64;
    int tid = threadIdx.x;
    int w = tid >> 6, lane = tid & 63, l15 = lane & 15, l4 = lane >> 4;
    f32x4 acc[4];
    #pragma unroll
    for (int j=0;j<4;++j) acc[j] = (f32x4){0.f,0.f,0.f,0.f};

    for (int i = tid; i < 576; i += 256) sv[i] = vin[(m0 + i/9)*9 + i%9];

    for (int kc0 = 0; kc0 < 2560; kc0 += 128){
        if (kc0) __syncthreads();
        for (int i = tid; i < 1024; i += 256){
            int r = i >> 4, jv = (i & 15)*8;
            *reinterpret_cast<uint4*>(&sA[r*136 + jv]) =
                *reinterpret_cast<const uint4*>(h5 + (size_t)(m0+r)*2560 + kc0 + jv);
            *reinterpret_cast<uint4*>(&sB[r*136 + jv]) =
                *reinterpret_cast<const uint4*>(pwh + (size_t)(nc0+r)*2560 + kc0 + jv);
        }
        __syncthreads();
        #pragma unroll
        for (int ks = 0; ks < 4; ++ks){
            half8 a = *reinterpret_cast<const half8*>(&sA[(w*16 + l15)*136 + ks*32 + l4*8]);
            #pragma unroll
            for (int j=0;j<4;++j){
                half8 bf = *reinterpret_cast<const half8*>(&sB[(j*16 + l15)*136 + ks*32 + l4*8]);
                acc[j] = __builtin_amdgcn_mfma_f32_16x16x32_f16(a, bf, acc[j], 0, 0, 0);
            }
        }
    }
    #pragma unroll
    for (int j=0;j<4;++j){
        int nc = nc0 + j*16 + l15;
        float bias = vproj_b[nc];
        #pragma unroll
        for (int r=0;r<4;++r){
            int ml = w*16 + l4*4 + r;
            float av = 0.f;
            #pragma unroll
            for (int k=0;k<9;++k) av = fmaf(sv[ml*9+k], vproj_w[nc*9+k], av);
            fusedh[(size_t)(m0+ml)*256 + nc] = f2h(lrelu_f(acc[j][r] + av + bias));
        }
    }
}

// ---------------------------------------------------------------------------
// GRU gate GEMM: gbuf[:,0:768] = fused @ wih^T ; gbuf[:,768:1536] = hx @ whh^T.
// grid(4, 24): y = half*12 + ntile. (R15-verified.)
// ---------------------------------------------------------------------------
__global__ __launch_bounds__(256) void k_ggemm(
    const u16* __restrict__ fusedh, const float* __restrict__ hx,
    const u16* __restrict__ wihh, const u16* __restrict__ whhh,
    float* __restrict__ gbuf)
{
    __shared__ __align__(16) u16 sA[64*136];
    __shared__ __align__(16) u16 sB[64*136];
    int m0 = blockIdx.x*64;
    int t  = blockIdx.y;
    int half = t / 12, nt = t - half*12;
    int n0 = nt*64;
    const u16* B = (half ? whhh : wihh) + (size_t)n0*256;
    int tid = threadIdx.x;
    int w = tid >> 6, lane = tid & 63, l15 = lane & 15, l4 = lane >> 4;
    f32x4 acc[4];
    #pragma unroll
    for (int j=0;j<4;++j) acc[j] = (f32x4){0.f,0.f,0.f,0.f};

    for (int kc0 = 0; kc0 < 256; kc0 += 128){
        if (kc0) __syncthreads();
        for (int i = tid; i < 1024; i += 256){
            int r = i >> 4, jv = (i & 15)*8;
            if (half == 0){
                *reinterpret_cast<uint4*>(&sA[r*136 + jv]) =
                    *reinterpret_cast<const uint4*>(fusedh + (size_t)(m0+r)*256 + kc0 + jv);
            } else {
                const float* src = hx + (size_t)(m0+r)*256 + kc0 + jv;
                float4 f0 = *reinterpret_cast<const float4*>(src);
                float4 f1 = *reinterpret_cast<const float4*>(src+4);
                u16 v[8] = { f2h(f0.x),f2h(f0.y),f2h(f0.z),f2h(f0.w),
                             f2h(f1.x),f2h(f1.y),f2h(f1.z),f2h(f1.w) };
                *reinterpret_cast<uint4*>(&sA[r*136 + jv]) = *reinterpret_cast<uint4*>(v);
            }
            *reinterpret_cast<uint4*>(&sB[r*136 + jv]) =
                *reinterpret_cast<const uint4*>(B + (size_t)r*256 + kc0 + jv);
        }
        __syncthreads();
        #pragma unroll
        for (int ks = 0; ks < 4; ++ks){
            half8 a = *reinterpret_cast<const half8*>(&sA[(w*16 + l15)*136 + ks*32 + l4*8]);
            #pragma unroll
            for (int j=0;j<4;++j){
                half8 bf = *reinterpret_cast<const half8*>(&sB[(j*16 + l15)*136 + ks*32 + l4*8]);
                acc[j] = __builtin_amdgcn_mfma_f32_16x16x32_f16(a, bf, acc[j], 0, 0, 0);
            }
        }
    }
    #pragma unroll
    for (int j=0;j<4;++j){
        int nc = half*768 + n0 + j*16 + l15;
        #pragma unroll
        for (int r=0;r<4;++r){
            int m = m0 + w*16 + l4*4 + r;
            gbuf[(size_t)m*1536 + nc] = acc[j][r];
        }
    }
}

// ---------------------------------------------------------------------------
// Fused GRU gate + act head (R17: k_act's batch row == k_gate's block, so the
// final GEMV folds in after a __syncthreads; saves a launch + round trip).
// ---------------------------------------------------------------------------
__global__ __launch_bounds__(256) void k_gate_act(
    const float* __restrict__ gbuf, const float* __restrict__ hx,
    const float* __restrict__ bih, const float* __restrict__ bhh,
    const float* __restrict__ fc_w,
    float* __restrict__ hx_new, float* __restrict__ act)
{
    __shared__ float sh[256];
    int b = blockIdx.x, j = threadIdx.x;
    const float* g = gbuf + (size_t)b*1536;
    float ir = g[j]       + bih[j];
    float iz = g[256+j]   + bih[256+j];
    float in_= g[512+j]   + bih[512+j];
    float hr = g[768+j]   + bhh[j];
    float hz = g[1024+j]  + bhh[256+j];
    float hn = g[1280+j]  + bhh[512+j];
    float r = 1.f/(1.f+expf(-(ir+hr)));
    float z = 1.f/(1.f+expf(-(iz+hz)));
    float n = tanhf(in_ + r*hn);
    float h = (1.f-z)*n + z*hx[b*256+j];
    hx_new[b*256+j] = h;
    sh[j] = lrelu_f(h);
    __syncthreads();
    int w = j >> 6, lane = j & 63;
    const float* fw = fc_w + w*256;
    int k0 = lane*4;
    float a = sh[k0]*fw[k0] + sh[k0+1]*fw[k0+1] + sh[k0+2]*fw[k0+2] + sh[k0+3]*fw[k0+3];
    #pragma unroll
    for (int off = 32; off; off >>= 1) a += __shfl_down(a, off);
    if (lane == 0) act[b*4 + w] = a;
}

extern "C" void kernel_launch(void* const* d_in, const int* in_sizes, int n_in,
                              void* d_out, int out_size, void* d_ws, size_t ws_size,
                              hipStream_t stream)
{
    const float* x      = (const float*)d_in[0];
    const float* vin    = (const float*)d_in[1];
    const float* hx     = (const float*)d_in[2];
    const float* sc0_w  = (const float*)d_in[3];
    const float* bn0g   = (const float*)d_in[4];
    const float* bn0b   = (const float*)d_in[5];
    const float* bn0m   = (const float*)d_in[6];
    const float* bn0v   = (const float*)d_in[7];
    const float* sc1_w  = (const float*)d_in[8];
    const float* bn1g   = (const float*)d_in[9];
    const float* bn1b   = (const float*)d_in[10];
    const float* bn1m   = (const float*)d_in[11];
    const float* bn1v   = (const float*)d_in[12];
    const float* c2_w   = (const float*)d_in[13];
    const float* bn2g   = (const float*)d_in[14];
    const float* bn2b   = (const float*)d_in[15];
    const float* bn2m   = (const float*)d_in[16];
    const float* bn2v   = (const float*)d_in[17];
    const float* c3_w   = (const float*)d_in[18];
    const float* bn3g   = (const float*)d_in[19];
    const float* bn3b   = (const float*)d_in[20];
    const float* bn3m   = (const float*)d_in[21];
    const float* bn3v   = (const float*)d_in[22];
    const float* c4_w   = (const float*)d_in[23];
    const float* bn4g   = (const float*)d_in[24];
    const float* bn4b   = (const float*)d_in[25];
    const float* bn4m   = (const float*)d_in[26];
    const float* bn4v   = (const float*)d_in[27];
    const float* c5_w   = (const float*)d_in[28];
    const float* bn5g   = (const float*)d_in[29];
    const float* bn5b   = (const float*)d_in[30];
    const float* bn5m   = (const float*)d_in[31];
    const float* bn5v   = (const float*)d_in[32];
    const float* proj_w = (const float*)d_in[33];
    const float* vproj_w= (const float*)d_in[34];
    const float* vproj_b= (const float*)d_in[35];
    const float* gru_wih= (const float*)d_in[36];
    const float* gru_whh= (const float*)d_in[37];
    const float* gru_bih= (const float*)d_in[38];
    const float* gru_bhh= (const float*)d_in[39];
    const float* fc_w   = (const float*)d_in[40];

    char* base = (char*)d_ws;
    size_t off = 0;
    auto alloc = [&](size_t bytes)->char*{
        char* p = base + off; off += (bytes + 255) & ~(size_t)255; return p;
    };
    int* map0 = (int*)alloc((size_t)96*192*4);
    int* map1 = (int*)alloc((size_t)48*96*4);
    u16* wb0  = (u16*)alloc((size_t)32*2*128*2);
    u16* wb1  = (u16*)alloc((size_t)64*5*160*2);
    u16* wb2  = (u16*)alloc((size_t)64*3*192*2);
    u16* wb3  = (u16*)alloc((size_t)64*2*128*2);
    u16* wb4  = (u16*)alloc((size_t)128*3*192*2);
    u16* wb5  = (u16*)alloc((size_t)128*9*128*2);
    u16* pwh  = (u16*)alloc((size_t)256*2560*2);
    u16* wihh = (u16*)alloc((size_t)768*256*2);
    u16* whhh = (u16*)alloc((size_t)768*256*2);
    u16* xu   = (u16*)alloc((size_t)256*18432*8*2);   // xu0 only (xu1 folded)
    u16* h0   = (u16*)alloc((size_t)256*1953*32*2);
    u16* h1   = (u16*)alloc((size_t)256*465*64*2);
    u16* h2   = (u16*)alloc((size_t)256*377*64*2);
    u16* h3   = (u16*)alloc((size_t)256*84*64*2);
    u16* h4   = (u16*)alloc((size_t)256*48*128*2);
    u16* h5   = (u16*)alloc((size_t)256*20*128*2);
    u16* fusedh = (u16*)alloc((size_t)256*256*2);
    float* gbuf = (float*)alloc((size_t)256*1536*4);

    // ---- one-time prep (single launch, y-dispatched) ----
    PrepP pp = { map0, map1, sc0_w, sc1_w, wb0, wb1,
                 c2_w, c3_w, c4_w, c5_w, wb2, wb3, wb4, wb5,
                 proj_w, gru_wih, gru_whh, pwh, wihh, whhh };
    k_prep<<<dim3(2560, 11), 256, 0, stream>>>(pp);

    // ---- backbone (NHWC, MFMA f16, 2-D wave tiles) ----
    // k_nconv<CO,OW,NTOT,NB,IH,IW,KW,S,CI,TPC,NCH,KCm,KCp,WR,WC,WN,WM[,GATHER,INTOT]>
    k_xu0<<<dim3(72, 256), 256, 0, stream>>>(x, map0, xu);
    k_nconv<32,63,1953,16, 96,192, 5,3, 8,13,2, 128,136, 4,1,2,2>
        <<<256*16, 256, 0, stream>>>(xu, nullptr, wb0, bn0g,bn0b,bn0m,bn0v, h0);
    k_nconv<64,31,465,8, 48,96, 5,3, 32,5,5, 160,168, 2,2,2,2, 1,1953>
        <<<256*8, 256, 0, stream>>>(h0, map1, wb1, bn1g,bn1b,bn1m,bn1v, h1);
    k_nconv<64,29,377,6, 15,31, 3,1, 64,3,3, 192,200, 2,2,2,2>
        <<<256*6, 256, 0, stream>>>(h1, nullptr, wb2, bn2g,bn2b,bn2m,bn2v, h2);
    k_nconv<64,14,84,3, 13,29, 2,2, 64,2,2, 128,136, 2,2,1,2>
        <<<256*3, 256, 0, stream>>>(h2, nullptr, wb3, bn3g,bn3b,bn3m,bn3v, h3);
    k_nconv<128,12,48,3, 6,14, 3,1, 64,3,3, 192,200, 1,4,1,2>
        <<<256*3, 256, 0, stream>>>(h3, nullptr, wb4, bn4g,bn4b,bn4m,bn4v, h4);
    k_nconv<128,10,20,2, 4,12, 3,1, 128,1,9, 128,136, 1,4,1,2>
        <<<256*2, 256, 0, stream>>>(h4, nullptr, wb5, bn5g,bn5b,bn5m,bn5v, h5);

    // ---- head (MFMA GEMMs) ----
    k_head2<<<dim3(4,4), 256, 0, stream>>>(h5, pwh, vin, vproj_w, vproj_b, fusedh);
    k_ggemm<<<dim3(4,24), 256, 0, stream>>>(fusedh, hx, wihh, whhh, gbuf);
    float* outp = (float*)d_out;
    k_gate_act<<<256, 256, 0, stream>>>(gbuf, hx, gru_bih, gru_bhh, fc_w,
                                        outp + 1024, outp);
}